// Round 11
// baseline (91.315 us; speedup 1.0000x reference)
//
#include <hip/hip_runtime.h>
#include <hip/hip_bf16.h>
#include <math.h>

#define THREADS 256

constexpr int S   = 8;
constexpr int NPT = 64;
constexpr int SD  = 36;
constexpr float EPS = 1e-5f;

typedef float v4f __attribute__((ext_vector_type(4)));
typedef __attribute__((ext_vector_type(8))) short bf8;   // 8 bf16 (4 VGPR)
typedef __attribute__((ext_vector_type(4))) float f4;    // MFMA accumulator

__device__ __forceinline__ float lrelu(float x) { return fmaxf(x, 0.01f * x); }

// float -> bf16 via native HW conversion (RNE)
__device__ __forceinline__ unsigned short f2bf(float x) {
  return __builtin_bit_cast(unsigned short, __float2bfloat16(x));
}

// ==================== fragment packing (one-time prep) ====================
// B-fragment: frag f = kt*NT + nt; lane l holds n = nt*16 + (l&15),
// k = kt*32 + (l>>4)*8 + j, j=0..7.
// TS>0: 2-tap conv weight [2][CIN][N], tap stride TS (zero-pad c >= CIN).
// TS==0: flat [K][N]; if CIN>0, zero-pad k >= CIN.
__device__ __forceinline__ void pack_frag(const float* __restrict__ src, unsigned short* __restrict__ dst,
                                          int slot, int NT, int TS, int CIN, int N) {
  const int f = slot >> 6, l = slot & 63;
  const int nt = f % NT, kt = f / NT;
  const int n = nt * 16 + (l & 15), g = (l >> 4);
  unsigned short* d = dst + (size_t)f * 512 + l * 8;
#pragma unroll
  for (int j = 0; j < 8; ++j) {
    int k = kt * 32 + g * 8 + j;
    float v;
    if (TS > 0) { int tap = k / TS, c = k - tap * TS; v = (c < CIN) ? src[(tap * CIN + c) * N + n] : 0.f; }
    else        v = (CIN == 0 || k < CIN) ? src[k * N + n] : 0.f;
    d[j] = f2bf(v);
  }
}

// MW1 fragments with the L4 fold done on the fly:
// W1'[tap][c][n] = sum_d pw4[c][d] * mw1[tap][d][n]   (exact; L4 has no activation)
// Restructured: coalesced m-loads (lane n consecutive) + v4f pw4 loads.
__device__ __forceinline__ void pack_frag_fold(const float* __restrict__ pw4,
    const float* __restrict__ mw1, unsigned short* __restrict__ dst, int slot) {
  const int f = slot >> 6, l = slot & 63;     // NT = 8
  const int nt = f & 7, kt = f >> 3;
  const int n = nt * 16 + (l & 15), g = l >> 4;
  const int k0 = kt * 32 + g * 8;
  const int tap = k0 >> 7, c0 = k0 & 127;     // 8 consecutive c, single tap
  float acc[8] = {};
  const float* mcol  = mw1 + (size_t)tap * 128 * 128 + n;   // mw1[tap][d][n], d stride 128
  const float* pbase = pw4 + (size_t)c0 * 128;              // pw4[c0+j][d]
  for (int d4 = 0; d4 < 32; ++d4) {
    const int d0 = 4 * d4;
    float m0 = mcol[(size_t)(d0 + 0) * 128];
    float m1 = mcol[(size_t)(d0 + 1) * 128];
    float m2 = mcol[(size_t)(d0 + 2) * 128];
    float m3 = mcol[(size_t)(d0 + 3) * 128];
#pragma unroll
    for (int j = 0; j < 8; ++j) {
      v4f pv = *(const v4f*)(pbase + j * 128 + d0);
      acc[j] = fmaf(pv[0], m0, fmaf(pv[1], m1, fmaf(pv[2], m2, fmaf(pv[3], m3, acc[j]))));
    }
  }
  unsigned short* dd = dst + (size_t)f * 512 + l * 8;
#pragma unroll
  for (int j = 0; j < 8; ++j) dd[j] = f2bf(acc[j]);
}

// fragment-region offsets in u16 units (frag = 512 u16)
#define WOFF_PNW1 0
#define WOFF_PNW2 1024
#define WOFF_PNW3 3072
#define WOFF_MW1  11264
#define WOFF_MW2  44032
#define WOFF_MW3  60416
#define WOFF_MW4  68608
#define WOFF_MDW  76800
#define WOFF_SW1  142336
#define WOFF_SW2  154624
#define WOFF_SW3  171008
#define WOFF_SW4  179200
#define WOFF_SDW  187392
// total 494 frags = 252928 u16 = 505856 B

__global__ void prep_weights(const float* __restrict__ pw1, const float* __restrict__ pw2,
    const float* __restrict__ pw3,
    const float* __restrict__ pw4, const float* __restrict__ pb4,
    const float* __restrict__ mw1, const float* __restrict__ mb1,
    const float* __restrict__ mw2, const float* __restrict__ mw3,
    const float* __restrict__ mw4, const float* __restrict__ mdw,
    const float* __restrict__ sw1, const float* __restrict__ sw2, const float* __restrict__ sw3,
    const float* __restrict__ sw4, const float* __restrict__ sdw,
    unsigned short* __restrict__ wf, float* __restrict__ mb1p, float* __restrict__ mb1p7) {
  const int slot = blockIdx.x * 256 + threadIdx.x;
  if      (slot <   128) pack_frag(pw1,    wf + WOFF_PNW1, slot,          2,   0,   5,  32);
  else if (slot <   384) pack_frag(pw2,    wf + WOFF_PNW2, slot - 128,    4,   0,   0,  64);
  else if (slot <  1408) pack_frag(pw3,    wf + WOFF_PNW3, slot - 384,    8,   0,   0, 128);
  else if (slot <  5504) pack_frag_fold(pw4, mw1, wf + WOFF_MW1, slot - 1408);
  else if (slot <  7552) pack_frag(mw2,    wf + WOFF_MW2,  slot - 5504,   4, 128, 128,  64);
  else if (slot <  8576) pack_frag(mw3,    wf + WOFF_MW3,  slot - 7552,   4,  64,  64,  64);
  else if (slot <  9600) pack_frag(mw4,    wf + WOFF_MW4,  slot - 8576,   4,  64,  64,  64);
  else if (slot < 17792) pack_frag(mdw,    wf + WOFF_MDW,  slot - 9600,   8,   0,   0, 128);
  else if (slot < 19328) pack_frag(sw1,    wf + WOFF_SW1,  slot - 17792,  8,  48,  36, 128);
  else if (slot < 21376) pack_frag(sw2,    wf + WOFF_SW2,  slot - 19328,  4, 128, 128,  64);
  else if (slot < 22400) pack_frag(sw3,    wf + WOFF_SW3,  slot - 21376,  4,  64,  64,  64);
  else if (slot < 23424) pack_frag(sw4,    wf + WOFF_SW4,  slot - 22400,  4,  64,  64,  64);
  else if (slot < 31616) pack_frag(sdw,    wf + WOFF_SDW,  slot - 23424,  8,   0,   0, 128);
  else if (slot < 31744) {                  // conv1 bias, rows n<7 (both taps see pb4)
    const int n = slot - 31616;
    float a = mb1[n];
    for (int d = 0; d < 128; ++d)
      a = fmaf(pb4[d], mw1[(size_t)d * 128 + n] + mw1[(size_t)(128 + d) * 128 + n], a);
    mb1p[n] = a;
  } else if (slot < 31872) {                // conv1 bias, row n==7 (tap1 input is zero pad)
    const int n = slot - 31744;
    float a = mb1[n];
    for (int d = 0; d < 128; ++d) a = fmaf(pb4[d], mw1[(size_t)d * 128 + n], a);
    mb1p7[n] = a;
  }
}

// ==================== kernel 1: pointnet, all-MFMA, all norms in-register ====================
// Ends at xbar (L4 folded into the tail's conv1); writes 128 bf16 per (b,s).
__global__ __launch_bounds__(THREADS)
void pointnet_kernel(const float* __restrict__ fts,
    const unsigned short* __restrict__ w1f, const float* __restrict__ pg1, const float* __restrict__ pbe1,
    const unsigned short* __restrict__ w2f, const float* __restrict__ pg2, const float* __restrict__ pbe2,
    const unsigned short* __restrict__ w3f, const float* __restrict__ pg3, const float* __restrict__ pbe3,
    unsigned short* __restrict__ xbar_out)
{
  const int p = blockIdx.x;            // b*S + s
  const int t = threadIdx.x;
  const int l = t & 63, w = t >> 6;
  const int g = l >> 4, lc = l & 15;

  __shared__ unsigned short xinb[64 * 40];   // input bf16, K zero-padded to 32 (cols 32..39 unused)
  __shared__ unsigned short x1b[64 * 40];    // L1 normed (ch 0..31)
  __shared__ unsigned short x2b[64 * 72];    // L2 normed (ch 0..63)

  // hoist all B-fragment loads: issue early, hide L2 latency under staging + L1
  bf8 bfrag_w1 = {};
  if (w < 2) bfrag_w1 = *(const bf8*)(w1f + ((size_t)w * 64 + l) * 8);
  bf8 bfrag_w2 = *(const bf8*)(w2f + ((size_t)w * 64 + l) * 8);
  bf8 bf3[2][2];
#pragma unroll
  for (int ntl = 0; ntl < 2; ++ntl)
#pragma unroll
    for (int kt = 0; kt < 2; ++kt)
      bf3[ntl][kt] = *(const bf8*)(w3f + ((size_t)(kt * 8 + (2 * w + ntl)) * 64 + l) * 8);

  // stage input: thread t owns row t>>2, u32 column slot (t&3)+4k, k=0..3.
  {
    const float* src = fts + (size_t)p * 320;
    unsigned* xz = (unsigned*)xinb;
    const int row = t >> 2, cp = t & 3;
    const float* sr = src + row * 5;
    unsigned v0 = 0u;
    if (cp == 0)      v0 = (unsigned)f2bf(sr[0]) | ((unsigned)f2bf(sr[1]) << 16);
    else if (cp == 1) v0 = (unsigned)f2bf(sr[2]) | ((unsigned)f2bf(sr[3]) << 16);
    else if (cp == 2) v0 = (unsigned)f2bf(sr[4]);
    unsigned* xr = xz + row * 20;
    xr[cp]      = v0;
    xr[cp + 4]  = 0u;
    xr[cp + 8]  = 0u;
    xr[cp + 12] = 0u;
  }
  __syncthreads();

  // ---- L1 MFMA [64x32(k,pad5)]@[32x32]; waves 0,1 own 16 channels each ----
  if (w < 2) {
    f4 c1[4];
#pragma unroll
    for (int mt = 0; mt < 4; ++mt) c1[mt] = f4{0.f, 0.f, 0.f, 0.f};
#pragma unroll
    for (int mt = 0; mt < 4; ++mt) {
      bf8 afrag = *(const bf8*)(xinb + (mt * 16 + lc) * 40 + g * 8);
      c1[mt] = __builtin_amdgcn_mfma_f32_16x16x32_bf16(afrag, bfrag_w1, c1[mt], 0, 0, 0);
    }
    float s = 0.f, q = 0.f;
#pragma unroll
    for (int mt = 0; mt < 4; ++mt)
#pragma unroll
      for (int r = 0; r < 4; ++r) { float v = c1[mt][r]; s += v; q = fmaf(v, v, q); }
    s += __shfl_xor(s, 16, 64); s += __shfl_xor(s, 32, 64);
    q += __shfl_xor(q, 16, 64); q += __shfl_xor(q, 32, 64);
    const int ch = w * 16 + lc;
    float mu  = s * (1.f / NPT);
    float inv = rsqrtf(q * (1.f / NPT) - mu * mu + EPS);
    float a = inv * pg1[ch];
    float bb = fmaf(-mu, a, pbe1[ch]);
#pragma unroll
    for (int mt = 0; mt < 4; ++mt)
#pragma unroll
      for (int r = 0; r < 4; ++r) {
        int row = mt * 16 + g * 4 + r;
        x1b[row * 40 + ch] = f2bf(lrelu(fmaf(c1[mt][r], a, bb)));
      }
  }
  __syncthreads();

  // ---- L2 MFMA [64x32]@[32x64]; wave w owns channels 16w..16w+15 ----
  f4 c2[4];
#pragma unroll
  for (int mt = 0; mt < 4; ++mt) c2[mt] = f4{0.f, 0.f, 0.f, 0.f};
#pragma unroll
  for (int mt = 0; mt < 4; ++mt) {
    bf8 afrag = *(const bf8*)(x1b + (mt * 16 + lc) * 40 + g * 8);
    c2[mt] = __builtin_amdgcn_mfma_f32_16x16x32_bf16(afrag, bfrag_w2, c2[mt], 0, 0, 0);
  }
  {
    float s = 0.f, q = 0.f;
#pragma unroll
    for (int mt = 0; mt < 4; ++mt)
#pragma unroll
      for (int r = 0; r < 4; ++r) { float v = c2[mt][r]; s += v; q = fmaf(v, v, q); }
    s += __shfl_xor(s, 16, 64); s += __shfl_xor(s, 32, 64);
    q += __shfl_xor(q, 16, 64); q += __shfl_xor(q, 32, 64);
    const int ch = w * 16 + lc;
    float mu  = s * (1.f / NPT);
    float inv = rsqrtf(q * (1.f / NPT) - mu * mu + EPS);
    float a = inv * pg2[ch];
    float bb = fmaf(-mu, a, pbe2[ch]);
#pragma unroll
    for (int mt = 0; mt < 4; ++mt)
#pragma unroll
      for (int r = 0; r < 4; ++r) {
        int row = mt * 16 + g * 4 + r;
        x2b[row * 72 + ch] = f2bf(lrelu(fmaf(c2[mt][r], a, bb)));
      }
  }
  __syncthreads();

  // ---- L3 MFMA [64x64]@[64x128]; wave w owns channels 32w..32w+31 ----
  f4 c3[4][2];
#pragma unroll
  for (int mt = 0; mt < 4; ++mt)
#pragma unroll
    for (int n = 0; n < 2; ++n) c3[mt][n] = f4{0.f, 0.f, 0.f, 0.f};
#pragma unroll
  for (int mt = 0; mt < 4; ++mt)
#pragma unroll
    for (int kt = 0; kt < 2; ++kt) {
      bf8 afrag = *(const bf8*)(x2b + (mt * 16 + lc) * 72 + kt * 32 + g * 8);
#pragma unroll
      for (int ntl = 0; ntl < 2; ++ntl)
        c3[mt][ntl] = __builtin_amdgcn_mfma_f32_16x16x32_bf16(afrag, bf3[ntl][kt], c3[mt][ntl], 0, 0, 0);
    }

  // ---- inorm3 + lrelu + mean over n, in-register; write xbar bf16 to global ----
#pragma unroll
  for (int ntl = 0; ntl < 2; ++ntl) {
    float s = 0.f, q = 0.f;
#pragma unroll
    for (int mt = 0; mt < 4; ++mt)
#pragma unroll
      for (int r = 0; r < 4; ++r) { float v = c3[mt][ntl][r]; s += v; q = fmaf(v, v, q); }
    s += __shfl_xor(s, 16, 64); s += __shfl_xor(s, 32, 64);
    q += __shfl_xor(q, 16, 64); q += __shfl_xor(q, 32, 64);
    const int ch = w * 32 + ntl * 16 + lc;
    float mu  = s * (1.f / NPT);
    float inv = rsqrtf(q * (1.f / NPT) - mu * mu + EPS);
    float a = inv * pg3[ch];
    float bb = fmaf(-mu, a, pbe3[ch]);
    float m = 0.f;
#pragma unroll
    for (int mt = 0; mt < 4; ++mt)
#pragma unroll
      for (int r = 0; r < 4; ++r) m += lrelu(fmaf(c3[mt][ntl][r], a, bb));
    m += __shfl_xor(m, 16, 64); m += __shfl_xor(m, 32, 64);
    if (g == 0) xbar_out[(size_t)p * 128 + ch] = f2bf(m * (1.f / NPT));
  }
}

// ==================== kernel 2: MFMA tail + head, both branches in one block ====================
// A layout in LDS: [b_loc][9][SP] bf16, row 8 = zeros (2-tap overflow).
template<int KT, int NT, int TS, int SPI, int SPO, bool ACT>
__device__ __forceinline__ void mfma_conv(const unsigned short* __restrict__ xin,
    unsigned short* __restrict__ xout, const unsigned short* __restrict__ wfr,
    const float* __restrict__ bias, const float* __restrict__ bias7, int w, int l) {
  const int g = l >> 4, lc = l & 15;
  const int arow = w * 16 + lc, abl = arow >> 3, an = arow & 7;
  f4 acc[NT];
#pragma unroll
  for (int nt = 0; nt < NT; ++nt) acc[nt] = f4{0.f, 0.f, 0.f, 0.f};
#pragma unroll
  for (int kt = 0; kt < KT; ++kt) {
    const int k0 = kt * 32 + g * 8;
    const int tap = k0 / TS, c = k0 - tap * TS;
    bf8 a = *(const bf8*)(xin + (abl * 9 + an + tap) * SPI + c);
#pragma unroll
    for (int nt = 0; nt < NT; ++nt) {
      bf8 b = *(const bf8*)(wfr + ((size_t)(kt * NT + nt) * 64 + l) * 8);
      acc[nt] = __builtin_amdgcn_mfma_f32_16x16x32_bf16(a, b, acc[nt], 0, 0, 0);
    }
  }
  const int orow0 = w * 16 + g * 4;
#pragma unroll
  for (int nt = 0; nt < NT; ++nt) {
    const float bv  = bias[nt * 16 + lc];
    const float bv7 = bias7[nt * 16 + lc];
#pragma unroll
    for (int r = 0; r < 4; ++r) {
      const int rr = orow0 + r, obl = rr >> 3, on = rr & 7;
      float v = acc[nt][r] + (on == 7 ? bv7 : bv);
      if (ACT) v = lrelu(v);
      xout[(obl * 9 + on) * SPO + nt * 16 + lc] = f2bf(v);
    }
  }
}

// dense 512->128 over [8 b][8 n][64 ch] (K-split over 4 waves, partials to LDS)
__device__ __forceinline__ void mfma_dense512(const unsigned short* __restrict__ xin,
    float* __restrict__ P, const unsigned short* __restrict__ wfr, int w, int l) {
  const int g = l >> 4, lc = l & 15;
  const int bl = lc & 7;                 // rows 8-15 duplicate rows 0-7
  f4 acc[8];
#pragma unroll
  for (int nt = 0; nt < 8; ++nt) acc[nt] = f4{0.f, 0.f, 0.f, 0.f};
#pragma unroll
  for (int kt2 = 0; kt2 < 4; ++kt2) {
    const int kt = w * 4 + kt2;
    const int k0 = kt * 32 + g * 8;
    const int n = k0 >> 6, c = k0 & 63;
    bf8 a = *(const bf8*)(xin + (bl * 9 + n) * 72 + c);
#pragma unroll
    for (int nt = 0; nt < 8; ++nt) {
      bf8 b = *(const bf8*)(wfr + ((size_t)(kt * 8 + nt) * 64 + l) * 8);
      acc[nt] = __builtin_amdgcn_mfma_f32_16x16x32_bf16(a, b, acc[nt], 0, 0, 0);
    }
  }
  if (g < 2) {
#pragma unroll
    for (int nt = 0; nt < 8; ++nt)
#pragma unroll
      for (int r = 0; r < 4; ++r) {
        const int rr = g * 4 + r;       // 0..7
        P[(w * 8 + rr) * 128 + nt * 16 + lc] = acc[nt][r];
      }
  }
}

// small dense, wave-private (no barriers)
template<int CIN, int COUT, bool ACT>
__device__ __forceinline__ void wave_dense(const float* __restrict__ in, float* __restrict__ out,
                                           const float* __restrict__ W, const float* __restrict__ bias, int l) {
  if constexpr (COUT >= 64) {
    constexpr int NC = COUT / 64;
    const int d0 = l * NC;
    float acc[NC];
#pragma unroll
    for (int k = 0; k < NC; ++k) acc[k] = bias[d0 + k];
#pragma unroll 4
    for (int c4 = 0; c4 < CIN / 4; ++c4) {
      v4f x4 = *(const v4f*)(in + 4 * c4);
#pragma unroll
      for (int j = 0; j < 4; ++j) {
        const float* wr = W + (4 * c4 + j) * COUT + d0;
#pragma unroll
        for (int k = 0; k < NC; ++k) acc[k] = fmaf(x4[j], wr[k], acc[k]);
      }
    }
#pragma unroll
    for (int k = 0; k < NC; ++k) out[d0 + k] = ACT ? lrelu(acc[k]) : acc[k];
  } else {
    if (l < COUT) {
      float acc = bias[l];
#pragma unroll 4
      for (int c4 = 0; c4 < CIN / 4; ++c4) {
        v4f x4 = *(const v4f*)(in + 4 * c4);
#pragma unroll
        for (int j = 0; j < 4; ++j) acc = fmaf(x4[j], W[(4 * c4 + j) * COUT + l], acc);
      }
      out[l] = ACT ? lrelu(acc) : acc;
    }
  }
}

__global__ __launch_bounds__(512)
void tail_head_kernel(const unsigned short* __restrict__ xbar, const float* __restrict__ state,
    const unsigned short* __restrict__ wf,
    const float* __restrict__ mb1p, const float* __restrict__ mb1p7,
    const float* __restrict__ mb2, const float* __restrict__ mb3,
    const float* __restrict__ mb4, const float* __restrict__ mdb,
    const float* __restrict__ sb1, const float* __restrict__ sb2, const float* __restrict__ sb3,
    const float* __restrict__ sb4, const float* __restrict__ sdb,
    const float* __restrict__ cw1, const float* __restrict__ cb1,
    const float* __restrict__ cw2, const float* __restrict__ cb2,
    const float* __restrict__ cw3, const float* __restrict__ cb3,
    const float* __restrict__ cw4, const float* __restrict__ cb4,
    float* __restrict__ out)
{
  const int t = threadIdx.x, l = t & 63, w = t >> 6;
  const int wl = w & 3;                // wave within branch
  const bool merge = w < 4;
  const int tb = t & 255;              // thread within branch
  const int bg = blockIdx.x;           // group of 8 b's

  __shared__ unsigned short lds[2][24768];     // 99 KB: region 0 = merge, 1 = states
  unsigned short* base = lds[merge ? 0 : 1];
  unsigned short* BufX = base;                 // [8][9][136] xin / L3-out [8][9][72] / partials
  unsigned short* BufY = base + 9792;          // L1-out [8][9][136] / L4-out [8][9][72]
  unsigned short* BufZ = base + 19584;         // L2-out [8][9][72]

  // zero: BufX fully; BufY row-8 (stride 136); BufZ row-8 (stride 72)
  { unsigned* z = (unsigned*)BufX; for (int i = tb; i < 4896; i += 256) z[i] = 0; }
  for (int i = tb; i < 8 * 136; i += 256) BufY[((i / 136) * 9 + 8) * 136 + (i % 136)] = 0;
  for (int i = tb; i < 8 * 72;  i += 256) BufZ[((i / 72)  * 9 + 8) * 72  + (i % 72)]  = 0;

  if (merge) {
    for (int i = tb; i < 1024; i += 256) {     // 8b x 8n x 16 chunks of 8 bf16
      int bl = i >> 7, rem = i & 127, n = rem >> 4, sl = rem & 15;
      bf8 v = *(const bf8*)(xbar + (size_t)((bg * 8 + bl) * 8 + n) * 128 + sl * 8);
      *(bf8*)(BufX + (bl * 9 + n) * 136 + sl * 8) = v;
    }
  } else {
    for (int i = tb; i < 2304; i += 256) {     // 8b x 8n x 36
      int bl = i / 288, rem = i % 288, n = rem / 36, c = rem % 36;
      BufX[(bl * 9 + n) * 48 + c] = f2bf(state[((size_t)(bg * 8 + bl) * 8 + n) * 36 + c]);
    }
  }
  __syncthreads();

  if (merge) mfma_conv<8, 8, 128, 136, 136, true>(BufX, BufY, wf + WOFF_MW1, mb1p, mb1p7, wl, l);
  else       mfma_conv<3, 8,  48,  48, 136, true>(BufX, BufY, wf + WOFF_SW1, sb1, sb1, wl, l);
  __syncthreads();
  if (merge) mfma_conv<8, 4, 128, 136, 72, true>(BufY, BufZ, wf + WOFF_MW2, mb2, mb2, wl, l);
  else       mfma_conv<8, 4, 128, 136, 72, true>(BufY, BufZ, wf + WOFF_SW2, sb2, sb2, wl, l);
  // BufX is dead; set up L3's zero row-8 (stride 72)
  __syncthreads();
  for (int i = tb; i < 8 * 72; i += 256) BufX[((i / 72) * 9 + 8) * 72 + (i % 72)] = 0;
  __syncthreads();
  if (merge) mfma_conv<4, 4, 64, 72, 72, true>(BufZ, BufX, wf + WOFF_MW3, mb3, mb3, wl, l);
  else       mfma_conv<4, 4, 64, 72, 72, true>(BufZ, BufX, wf + WOFF_SW3, sb3, sb3, wl, l);
  __syncthreads();
  if (merge) mfma_conv<4, 4, 64, 72, 72, true >(BufX, BufY, wf + WOFF_MW4, mb4, mb4, wl, l);
  else       mfma_conv<4, 4, 64, 72, 72, false>(BufX, BufY, wf + WOFF_SW4, sb4, sb4, wl, l);
  __syncthreads();

  float* P = (float*)base;                     // 16 KB partials (BufX region, dead)
  mfma_dense512(BufY, P, wf + (merge ? WOFF_MDW : WOFF_SDW), wl, l);
  __syncthreads();

  // ---- cat assembly (f32) into merge BufY (dead); then head, one wave per b ----
  float* P_m = (float*)lds[0];
  float* P_s = (float*)lds[1];
  float* cat = (float*)(lds[0] + 9792);        // [8 b][256]
  for (int i = t; i < 2048; i += 512) {
    int b = i >> 8, c = i & 255;
    float v;
    if (c < 128)
      v = mdb[c] + P_m[b * 128 + c] + P_m[(8 + b) * 128 + c]
                 + P_m[(16 + b) * 128 + c] + P_m[(24 + b) * 128 + c];
    else {
      int ch = c & 127;
      v = sdb[ch] + P_s[b * 128 + ch] + P_s[(8 + b) * 128 + ch]
                  + P_s[(16 + b) * 128 + ch] + P_s[(24 + b) * 128 + ch];
    }
    cat[b * 256 + c] = v;
  }
  __syncthreads();

  // head: wave w handles b_loc = w; hb is wave-private (no barriers needed)
  float* hb = (float*)(lds[1] + 9792) + w * 240;   // h1 128 | h2 64 | h3 32 (+pad)
  wave_dense<256, 128, true>(cat + w * 256, hb, cw1, cb1, l);
  wave_dense<128, 64, true>(hb, hb + 128, cw2, cb2, l);
  wave_dense<64, 32, true>(hb + 128, hb + 192, cw3, cb3, l);
  if (l < 4) {
    float acc = cb4[l];
#pragma unroll
    for (int c = 0; c < 32; ++c) acc = fmaf(hb[192 + c], cw4[c * 4 + l], acc);
    const int b = bg * 8 + w;
    out[(size_t)b * 4 + l] = (l == 0) ? 21.f / (1.f + expf(-acc)) : 6.f * tanhf(acc);
  }
}

extern "C" void kernel_launch(void* const* d_in, const int* in_sizes, int n_in,
                              void* d_out, int out_size, void* d_ws, size_t ws_size,
                              hipStream_t stream) {
  const float* p[44];
  for (int i = 0; i < 44; ++i) p[i] = (const float*)d_in[i];

  unsigned short* xbar_bf = (unsigned short*)d_ws;                     // 2 MB
  unsigned short* wf = (unsigned short*)((char*)d_ws + 2097152);       // 505856 B
  float* mb1p  = (float*)((char*)d_ws + 2603008);                      // 512 B
  float* mb1p7 = (float*)((char*)d_ws + 2603520);                      // 512 B

  prep_weights<<<125, THREADS, 0, stream>>>(
      p[2], p[6], p[10],
      p[14], p[15], p[16], p[17],
      p[18], p[20], p[22], p[24],
      p[26], p[28], p[30], p[32], p[34],
      wf, mb1p, mb1p7);

  pointnet_kernel<<<1024 * S, THREADS, 0, stream>>>(
      p[0],
      wf + WOFF_PNW1, p[4], p[5],
      wf + WOFF_PNW2, p[8], p[9],
      wf + WOFF_PNW3, p[12], p[13],
      xbar_bf);

  tail_head_kernel<<<128, 512, 0, stream>>>(
      xbar_bf, p[1], wf,
      mb1p, mb1p7, p[19], p[21], p[23], p[25],
      p[27], p[29], p[31], p[33], p[35],
      p[36], p[37], p[38], p[39], p[40], p[41], p[42], p[43],
      (float*)d_out);
}

// Round 12
// 80.440 us; speedup vs baseline: 1.1352x; 1.1352x over previous
//
#include <hip/hip_runtime.h>
#include <hip/hip_bf16.h>
#include <math.h>

#define THREADS 256

constexpr int S   = 8;
constexpr int NPT = 64;
constexpr int SD  = 36;
constexpr float EPS = 1e-5f;

typedef float v4f __attribute__((ext_vector_type(4)));
typedef __attribute__((ext_vector_type(8))) short bf8;   // 8 bf16 (4 VGPR)
typedef __attribute__((ext_vector_type(4))) float f4;    // MFMA accumulator

__device__ __forceinline__ float lrelu(float x) { return fmaxf(x, 0.01f * x); }

// float -> bf16 via native HW conversion (RNE)
__device__ __forceinline__ unsigned short f2bf(float x) {
  return __builtin_bit_cast(unsigned short, __float2bfloat16(x));
}

// ==================== fragment packing (one-time prep) ====================
// B-fragment: frag f = kt*NT + nt; lane l holds n = nt*16 + (l&15),
// k = kt*32 + (l>>4)*8 + j, j=0..7.
// TS>0: 2-tap conv weight [2][CIN][N], tap stride TS (zero-pad c >= CIN).
// TS==0: flat [K][N]; if CIN>0, zero-pad k >= CIN.
__device__ __forceinline__ void pack_frag(const float* __restrict__ src, unsigned short* __restrict__ dst,
                                          int slot, int NT, int TS, int CIN, int N) {
  const int f = slot >> 6, l = slot & 63;
  const int nt = f % NT, kt = f / NT;
  const int n = nt * 16 + (l & 15), g = (l >> 4);
  unsigned short* d = dst + (size_t)f * 512 + l * 8;
#pragma unroll
  for (int j = 0; j < 8; ++j) {
    int k = kt * 32 + g * 8 + j;
    float v;
    if (TS > 0) { int tap = k / TS, c = k - tap * TS; v = (c < CIN) ? src[(tap * CIN + c) * N + n] : 0.f; }
    else        v = (CIN == 0 || k < CIN) ? src[k * N + n] : 0.f;
    d[j] = f2bf(v);
  }
}

// MW1 fragments with the L4 fold done on the fly:
// W1'[tap][c][n] = sum_d pw4[c][d] * mw1[tap][d][n]   (exact; L4 has no activation)
// Coalesced m-loads (lane n consecutive) + v4f pw4 loads.
__device__ __forceinline__ void pack_frag_fold(const float* __restrict__ pw4,
    const float* __restrict__ mw1, unsigned short* __restrict__ dst, int slot) {
  const int f = slot >> 6, l = slot & 63;     // NT = 8
  const int nt = f & 7, kt = f >> 3;
  const int n = nt * 16 + (l & 15), g = l >> 4;
  const int k0 = kt * 32 + g * 8;
  const int tap = k0 >> 7, c0 = k0 & 127;     // 8 consecutive c, single tap
  float acc[8] = {};
  const float* mcol  = mw1 + (size_t)tap * 128 * 128 + n;   // mw1[tap][d][n], d stride 128
  const float* pbase = pw4 + (size_t)c0 * 128;              // pw4[c0+j][d]
  for (int d4 = 0; d4 < 32; ++d4) {
    const int d0 = 4 * d4;
    float m0 = mcol[(size_t)(d0 + 0) * 128];
    float m1 = mcol[(size_t)(d0 + 1) * 128];
    float m2 = mcol[(size_t)(d0 + 2) * 128];
    float m3 = mcol[(size_t)(d0 + 3) * 128];
#pragma unroll
    for (int j = 0; j < 8; ++j) {
      v4f pv = *(const v4f*)(pbase + j * 128 + d0);
      acc[j] = fmaf(pv[0], m0, fmaf(pv[1], m1, fmaf(pv[2], m2, fmaf(pv[3], m3, acc[j]))));
    }
  }
  unsigned short* dd = dst + (size_t)f * 512 + l * 8;
#pragma unroll
  for (int j = 0; j < 8; ++j) dd[j] = f2bf(acc[j]);
}

// fragment-region offsets in u16 units (frag = 512 u16)
#define WOFF_PNW1 0
#define WOFF_PNW2 1024
#define WOFF_PNW3 3072
#define WOFF_MW1  11264
#define WOFF_MW2  44032
#define WOFF_MW3  60416
#define WOFF_MW4  68608
#define WOFF_MDW  76800
#define WOFF_SW1  142336
#define WOFF_SW2  154624
#define WOFF_SW3  171008
#define WOFF_SW4  179200
#define WOFF_SDW  187392
// total 494 frags = 252928 u16 = 505856 B

__global__ void prep_weights(const float* __restrict__ pw1, const float* __restrict__ pw2,
    const float* __restrict__ pw3,
    const float* __restrict__ pw4, const float* __restrict__ pb4,
    const float* __restrict__ mw1, const float* __restrict__ mb1,
    const float* __restrict__ mw2, const float* __restrict__ mw3,
    const float* __restrict__ mw4, const float* __restrict__ mdw,
    const float* __restrict__ sw1, const float* __restrict__ sw2, const float* __restrict__ sw3,
    const float* __restrict__ sw4, const float* __restrict__ sdw,
    unsigned short* __restrict__ wf, float* __restrict__ mb1p, float* __restrict__ mb1p7) {
  const int slot = blockIdx.x * 256 + threadIdx.x;
  if      (slot <   128) pack_frag(pw1,    wf + WOFF_PNW1, slot,          2,   0,   5,  32);
  else if (slot <   384) pack_frag(pw2,    wf + WOFF_PNW2, slot - 128,    4,   0,   0,  64);
  else if (slot <  1408) pack_frag(pw3,    wf + WOFF_PNW3, slot - 384,    8,   0,   0, 128);
  else if (slot <  5504) pack_frag_fold(pw4, mw1, wf + WOFF_MW1, slot - 1408);
  else if (slot <  7552) pack_frag(mw2,    wf + WOFF_MW2,  slot - 5504,   4, 128, 128,  64);
  else if (slot <  8576) pack_frag(mw3,    wf + WOFF_MW3,  slot - 7552,   4,  64,  64,  64);
  else if (slot <  9600) pack_frag(mw4,    wf + WOFF_MW4,  slot - 8576,   4,  64,  64,  64);
  else if (slot < 17792) pack_frag(mdw,    wf + WOFF_MDW,  slot - 9600,   8,   0,   0, 128);
  else if (slot < 19328) pack_frag(sw1,    wf + WOFF_SW1,  slot - 17792,  8,  48,  36, 128);
  else if (slot < 21376) pack_frag(sw2,    wf + WOFF_SW2,  slot - 19328,  4, 128, 128,  64);
  else if (slot < 22400) pack_frag(sw3,    wf + WOFF_SW3,  slot - 21376,  4,  64,  64,  64);
  else if (slot < 23424) pack_frag(sw4,    wf + WOFF_SW4,  slot - 22400,  4,  64,  64,  64);
  else if (slot < 31616) pack_frag(sdw,    wf + WOFF_SDW,  slot - 23424,  8,   0,   0, 128);
  else if (slot < 31744) {                  // conv1 bias, rows n<7 (both taps see pb4)
    const int n = slot - 31616;
    float a = mb1[n];
    for (int d = 0; d < 128; ++d)
      a = fmaf(pb4[d], mw1[(size_t)d * 128 + n] + mw1[(size_t)(128 + d) * 128 + n], a);
    mb1p[n] = a;
  } else if (slot < 31872) {                // conv1 bias, row n==7 (tap1 input is zero pad)
    const int n = slot - 31744;
    float a = mb1[n];
    for (int d = 0; d < 128; ++d) a = fmaf(pb4[d], mw1[(size_t)d * 128 + n], a);
    mb1p7[n] = a;
  }
}

// ==================== kernel 1: pointnet, all-MFMA, all norms in-register ====================
// Ends at xbar (L4 folded into the tail's conv1); writes 128 bf16 per (b,s).
__global__ __launch_bounds__(THREADS)
void pointnet_kernel(const float* __restrict__ fts,
    const unsigned short* __restrict__ w1f, const float* __restrict__ pg1, const float* __restrict__ pbe1,
    const unsigned short* __restrict__ w2f, const float* __restrict__ pg2, const float* __restrict__ pbe2,
    const unsigned short* __restrict__ w3f, const float* __restrict__ pg3, const float* __restrict__ pbe3,
    unsigned short* __restrict__ xbar_out)
{
  const int p = blockIdx.x;            // b*S + s
  const int t = threadIdx.x;
  const int l = t & 63, w = t >> 6;
  const int g = l >> 4, lc = l & 15;

  __shared__ unsigned short xinb[64 * 40];   // input bf16, K zero-padded to 32 (cols 32..39 unused)
  __shared__ unsigned short x1b[64 * 40];    // L1 normed (ch 0..31)
  __shared__ unsigned short x2b[64 * 72];    // L2 normed (ch 0..63)

  // stage input: thread t owns row t>>2, u32 column slot (t&3)+4k, k=0..3.
  // only k=0, (t&3)<3 carries data (ch 0..4); the rest is the K-pad zeros.
  {
    const float* src = fts + (size_t)p * 320;
    unsigned* xz = (unsigned*)xinb;
    const int row = t >> 2, cp = t & 3;
    const float* sr = src + row * 5;
    unsigned v0 = 0u;
    if (cp == 0)      v0 = (unsigned)f2bf(sr[0]) | ((unsigned)f2bf(sr[1]) << 16);
    else if (cp == 1) v0 = (unsigned)f2bf(sr[2]) | ((unsigned)f2bf(sr[3]) << 16);
    else if (cp == 2) v0 = (unsigned)f2bf(sr[4]);
    unsigned* xr = xz + row * 20;
    xr[cp]      = v0;
    xr[cp + 4]  = 0u;
    xr[cp + 8]  = 0u;
    xr[cp + 12] = 0u;
  }
  __syncthreads();

  // ---- L1 MFMA [64x32(k,pad5)]@[32x32]; waves 0,1 own 16 channels each ----
  if (w < 2) {
    f4 c1[4];
#pragma unroll
    for (int mt = 0; mt < 4; ++mt) c1[mt] = f4{0.f, 0.f, 0.f, 0.f};
    bf8 bfrag = *(const bf8*)(w1f + ((size_t)w * 64 + l) * 8);
#pragma unroll
    for (int mt = 0; mt < 4; ++mt) {
      bf8 afrag = *(const bf8*)(xinb + (mt * 16 + lc) * 40 + g * 8);
      c1[mt] = __builtin_amdgcn_mfma_f32_16x16x32_bf16(afrag, bfrag, c1[mt], 0, 0, 0);
    }
    float s = 0.f, q = 0.f;
#pragma unroll
    for (int mt = 0; mt < 4; ++mt)
#pragma unroll
      for (int r = 0; r < 4; ++r) { float v = c1[mt][r]; s += v; q = fmaf(v, v, q); }
    s += __shfl_xor(s, 16, 64); s += __shfl_xor(s, 32, 64);
    q += __shfl_xor(q, 16, 64); q += __shfl_xor(q, 32, 64);
    const int ch = w * 16 + lc;
    float mu  = s * (1.f / NPT);
    float inv = rsqrtf(q * (1.f / NPT) - mu * mu + EPS);
    float a = inv * pg1[ch];
    float bb = fmaf(-mu, a, pbe1[ch]);
#pragma unroll
    for (int mt = 0; mt < 4; ++mt)
#pragma unroll
      for (int r = 0; r < 4; ++r) {
        int row = mt * 16 + g * 4 + r;
        x1b[row * 40 + ch] = f2bf(lrelu(fmaf(c1[mt][r], a, bb)));
      }
  }
  __syncthreads();

  // ---- L2 MFMA [64x32]@[32x64]; wave w owns channels 16w..16w+15 ----
  f4 c2[4];
#pragma unroll
  for (int mt = 0; mt < 4; ++mt) c2[mt] = f4{0.f, 0.f, 0.f, 0.f};
  {
    bf8 bfrag = *(const bf8*)(w2f + ((size_t)w * 64 + l) * 8);
#pragma unroll
    for (int mt = 0; mt < 4; ++mt) {
      bf8 afrag = *(const bf8*)(x1b + (mt * 16 + lc) * 40 + g * 8);
      c2[mt] = __builtin_amdgcn_mfma_f32_16x16x32_bf16(afrag, bfrag, c2[mt], 0, 0, 0);
    }
  }
  {
    float s = 0.f, q = 0.f;
#pragma unroll
    for (int mt = 0; mt < 4; ++mt)
#pragma unroll
      for (int r = 0; r < 4; ++r) { float v = c2[mt][r]; s += v; q = fmaf(v, v, q); }
    s += __shfl_xor(s, 16, 64); s += __shfl_xor(s, 32, 64);
    q += __shfl_xor(q, 16, 64); q += __shfl_xor(q, 32, 64);
    const int ch = w * 16 + lc;
    float mu  = s * (1.f / NPT);
    float inv = rsqrtf(q * (1.f / NPT) - mu * mu + EPS);
    float a = inv * pg2[ch];
    float bb = fmaf(-mu, a, pbe2[ch]);
#pragma unroll
    for (int mt = 0; mt < 4; ++mt)
#pragma unroll
      for (int r = 0; r < 4; ++r) {
        int row = mt * 16 + g * 4 + r;
        x2b[row * 72 + ch] = f2bf(lrelu(fmaf(c2[mt][r], a, bb)));
      }
  }
  __syncthreads();

  // ---- L3 MFMA [64x64]@[64x128]; wave w owns channels 32w..32w+31 ----
  f4 c3[4][2];
#pragma unroll
  for (int mt = 0; mt < 4; ++mt)
#pragma unroll
    for (int n = 0; n < 2; ++n) c3[mt][n] = f4{0.f, 0.f, 0.f, 0.f};
  bf8 bf3[2][2];
#pragma unroll
  for (int ntl = 0; ntl < 2; ++ntl)
#pragma unroll
    for (int kt = 0; kt < 2; ++kt)
      bf3[ntl][kt] = *(const bf8*)(w3f + ((size_t)(kt * 8 + (2 * w + ntl)) * 64 + l) * 8);
#pragma unroll
  for (int mt = 0; mt < 4; ++mt)
#pragma unroll
    for (int kt = 0; kt < 2; ++kt) {
      bf8 afrag = *(const bf8*)(x2b + (mt * 16 + lc) * 72 + kt * 32 + g * 8);
#pragma unroll
      for (int ntl = 0; ntl < 2; ++ntl)
        c3[mt][ntl] = __builtin_amdgcn_mfma_f32_16x16x32_bf16(afrag, bf3[ntl][kt], c3[mt][ntl], 0, 0, 0);
    }

  // ---- inorm3 + lrelu + mean over n, in-register; write xbar bf16 to global ----
#pragma unroll
  for (int ntl = 0; ntl < 2; ++ntl) {
    float s = 0.f, q = 0.f;
#pragma unroll
    for (int mt = 0; mt < 4; ++mt)
#pragma unroll
      for (int r = 0; r < 4; ++r) { float v = c3[mt][ntl][r]; s += v; q = fmaf(v, v, q); }
    s += __shfl_xor(s, 16, 64); s += __shfl_xor(s, 32, 64);
    q += __shfl_xor(q, 16, 64); q += __shfl_xor(q, 32, 64);
    const int ch = w * 32 + ntl * 16 + lc;
    float mu  = s * (1.f / NPT);
    float inv = rsqrtf(q * (1.f / NPT) - mu * mu + EPS);
    float a = inv * pg3[ch];
    float bb = fmaf(-mu, a, pbe3[ch]);
    float m = 0.f;
#pragma unroll
    for (int mt = 0; mt < 4; ++mt)
#pragma unroll
      for (int r = 0; r < 4; ++r) m += lrelu(fmaf(c3[mt][ntl][r], a, bb));
    m += __shfl_xor(m, 16, 64); m += __shfl_xor(m, 32, 64);
    if (g == 0) xbar_out[(size_t)p * 128 + ch] = f2bf(m * (1.f / NPT));
  }
}

// ==================== kernel 2: MFMA tail, G=8 b's per block ====================
// A layout in LDS: [b_loc][9][SP] bf16, row 8 = zeros (2-tap overflow).
// bias7 applies to output rows with n==7 (folded-conv1 edge); pass bias7==bias otherwise.
template<int KT, int NT, int TS, int SPI, int SPO, bool ACT>
__device__ __forceinline__ void mfma_conv(const unsigned short* __restrict__ xin,
    unsigned short* __restrict__ xout, const unsigned short* __restrict__ wfr,
    const float* __restrict__ bias, const float* __restrict__ bias7, int w, int l) {
  const int g = l >> 4, lc = l & 15;
  const int arow = w * 16 + lc, abl = arow >> 3, an = arow & 7;
  f4 acc[NT];
#pragma unroll
  for (int nt = 0; nt < NT; ++nt) acc[nt] = f4{0.f, 0.f, 0.f, 0.f};
#pragma unroll
  for (int kt = 0; kt < KT; ++kt) {
    const int k0 = kt * 32 + g * 8;
    const int tap = k0 / TS, c = k0 - tap * TS;
    bf8 a = *(const bf8*)(xin + (abl * 9 + an + tap) * SPI + c);
#pragma unroll
    for (int nt = 0; nt < NT; ++nt) {
      bf8 b = *(const bf8*)(wfr + ((size_t)(kt * NT + nt) * 64 + l) * 8);
      acc[nt] = __builtin_amdgcn_mfma_f32_16x16x32_bf16(a, b, acc[nt], 0, 0, 0);
    }
  }
  const int orow0 = w * 16 + g * 4;
#pragma unroll
  for (int nt = 0; nt < NT; ++nt) {
    const float bv  = bias[nt * 16 + lc];
    const float bv7 = bias7[nt * 16 + lc];
#pragma unroll
    for (int r = 0; r < 4; ++r) {
      const int rr = orow0 + r, obl = rr >> 3, on = rr & 7;
      float v = acc[nt][r] + (on == 7 ? bv7 : bv);
      if (ACT) v = lrelu(v);
      xout[(obl * 9 + on) * SPO + nt * 16 + lc] = f2bf(v);
    }
  }
}

// dense 512->128 over [8 b][8 n][64 ch] (K-split over 4 waves, partials to LDS)
__device__ __forceinline__ void mfma_dense512(const unsigned short* __restrict__ xin,
    float* __restrict__ P, const unsigned short* __restrict__ wfr, int w, int l) {
  const int g = l >> 4, lc = l & 15;
  const int bl = lc & 7;                 // rows 8-15 duplicate rows 0-7
  f4 acc[8];
#pragma unroll
  for (int nt = 0; nt < 8; ++nt) acc[nt] = f4{0.f, 0.f, 0.f, 0.f};
#pragma unroll
  for (int kt2 = 0; kt2 < 4; ++kt2) {
    const int kt = w * 4 + kt2;
    const int k0 = kt * 32 + g * 8;
    const int n = k0 >> 6, c = k0 & 63;
    bf8 a = *(const bf8*)(xin + (bl * 9 + n) * 72 + c);
#pragma unroll
    for (int nt = 0; nt < 8; ++nt) {
      bf8 b = *(const bf8*)(wfr + ((size_t)(kt * 8 + nt) * 64 + l) * 8);
      acc[nt] = __builtin_amdgcn_mfma_f32_16x16x32_bf16(a, b, acc[nt], 0, 0, 0);
    }
  }
  if (g < 2) {
#pragma unroll
    for (int nt = 0; nt < 8; ++nt)
#pragma unroll
      for (int r = 0; r < 4; ++r) {
        const int rr = g * 4 + r;       // 0..7
        P[(w * 8 + rr) * 128 + nt * 16 + lc] = acc[nt][r];
      }
  }
}

__global__ __launch_bounds__(THREADS)
void tail_mfma_kernel(const unsigned short* __restrict__ xbar, const float* __restrict__ state,
    const unsigned short* __restrict__ wf,
    const float* __restrict__ mb1p, const float* __restrict__ mb1p7,
    const float* __restrict__ mb2, const float* __restrict__ mb3,
    const float* __restrict__ mb4, const float* __restrict__ mdb,
    const float* __restrict__ sb1, const float* __restrict__ sb2, const float* __restrict__ sb3,
    const float* __restrict__ sb4, const float* __restrict__ sdb,
    float* __restrict__ femb, float* __restrict__ semb)
{
  const int t = threadIdx.x, l = t & 63, w = t >> 6;
  const bool merge = blockIdx.x < 128;
  const int bg = merge ? blockIdx.x : blockIdx.x - 128;

  __shared__ unsigned short lds[24768];           // 49.5 KB
  unsigned short* BufX = lds;                     // [8][9][136] xin / L3-out [8][9][72] / partials
  unsigned short* BufY = lds + 9792;              // L1-out [8][9][136] / L4-out [8][9][72]
  unsigned short* BufZ = lds + 19584;             // L2-out [8][9][72]

  // zero: BufX fully; BufY row-8 (stride 136); BufZ row-8 (stride 72)
  { unsigned* z = (unsigned*)BufX; for (int i = t; i < 4896; i += THREADS) z[i] = 0; }
  for (int i = t; i < 8 * 136; i += THREADS) BufY[((i / 136) * 9 + 8) * 136 + (i % 136)] = 0;
  for (int i = t; i < 8 * 72;  i += THREADS) BufZ[((i / 72)  * 9 + 8) * 72  + (i % 72)]  = 0;

  if (merge) {
    for (int i = t; i < 1024; i += THREADS) {     // 8b x 8n x 16 chunks of 8 bf16
      int bl = i >> 7, rem = i & 127, n = rem >> 4, sl = rem & 15;
      bf8 v = *(const bf8*)(xbar + (size_t)((bg * 8 + bl) * 8 + n) * 128 + sl * 8);
      *(bf8*)(BufX + (bl * 9 + n) * 136 + sl * 8) = v;
    }
  } else {
    for (int i = t; i < 2304; i += THREADS) {     // 8b x 8n x 36
      int bl = i / 288, rem = i % 288, n = rem / 36, c = rem % 36;
      BufX[(bl * 9 + n) * 48 + c] = f2bf(state[((size_t)(bg * 8 + bl) * 8 + n) * 36 + c]);
    }
  }
  __syncthreads();

  if (merge) mfma_conv<8, 8, 128, 136, 136, true>(BufX, BufY, wf + WOFF_MW1, mb1p, mb1p7, w, l);
  else       mfma_conv<3, 8,  48,  48, 136, true>(BufX, BufY, wf + WOFF_SW1, sb1, sb1, w, l);
  __syncthreads();
  if (merge) mfma_conv<8, 4, 128, 136, 72, true>(BufY, BufZ, wf + WOFF_MW2, mb2, mb2, w, l);
  else       mfma_conv<8, 4, 128, 136, 72, true>(BufY, BufZ, wf + WOFF_SW2, sb2, sb2, w, l);
  // BufX is dead; set up L3's zero row-8 (stride 72)
  __syncthreads();
  for (int i = t; i < 8 * 72; i += THREADS) BufX[((i / 72) * 9 + 8) * 72 + (i % 72)] = 0;
  __syncthreads();
  if (merge) mfma_conv<4, 4, 64, 72, 72, true>(BufZ, BufX, wf + WOFF_MW3, mb3, mb3, w, l);
  else       mfma_conv<4, 4, 64, 72, 72, true>(BufZ, BufX, wf + WOFF_SW3, sb3, sb3, w, l);
  __syncthreads();
  if (merge) mfma_conv<4, 4, 64, 72, 72, true >(BufX, BufY, wf + WOFF_MW4, mb4, mb4, w, l);
  else       mfma_conv<4, 4, 64, 72, 72, false>(BufX, BufY, wf + WOFF_SW4, sb4, sb4, w, l);
  __syncthreads();

  float* P = (float*)lds;                         // 16 KB partials (BufX region, dead)
  mfma_dense512(BufY, P, wf + (merge ? WOFF_MDW : WOFF_SDW), w, l);
  __syncthreads();

  const float* bias = merge ? mdb : sdb;
  float* outg = (merge ? femb : semb) + (size_t)bg * 1024;
  for (int i = t; i < 1024; i += THREADS) {
    int ch = i & 127, b = i >> 7;
    outg[i] = bias[ch] + P[(0 * 8 + b) * 128 + ch] + P[(1 * 8 + b) * 128 + ch]
                       + P[(2 * 8 + b) * 128 + ch] + P[(3 * 8 + b) * 128 + ch];
  }
}

// ==================== kernel 3: control head, one wave per b (no barriers) ====================
template<int CIN, int COUT, bool ACT>
__device__ __forceinline__ void wave_dense(const float* __restrict__ in, float* __restrict__ out,
                                           const float* __restrict__ W, const float* __restrict__ bias, int l) {
  if constexpr (COUT >= 64) {
    constexpr int NC = COUT / 64;
    const int d0 = l * NC;
    float acc[NC];
#pragma unroll
    for (int k = 0; k < NC; ++k) acc[k] = bias[d0 + k];
#pragma unroll 4
    for (int c4 = 0; c4 < CIN / 4; ++c4) {
      v4f x4 = *(const v4f*)(in + 4 * c4);
#pragma unroll
      for (int j = 0; j < 4; ++j) {
        const float* wr = W + (4 * c4 + j) * COUT + d0;
#pragma unroll
        for (int k = 0; k < NC; ++k) acc[k] = fmaf(x4[j], wr[k], acc[k]);
      }
    }
#pragma unroll
    for (int k = 0; k < NC; ++k) out[d0 + k] = ACT ? lrelu(acc[k]) : acc[k];
  } else {
    if (l < COUT) {
      float acc = bias[l];
#pragma unroll 4
      for (int c4 = 0; c4 < CIN / 4; ++c4) {
        v4f x4 = *(const v4f*)(in + 4 * c4);
#pragma unroll
        for (int j = 0; j < 4; ++j) acc = fmaf(x4[j], W[(4 * c4 + j) * COUT + l], acc);
      }
      out[l] = ACT ? lrelu(acc) : acc;
    }
  }
}

__global__ __launch_bounds__(THREADS)
void head_kernel(const float* __restrict__ femb, const float* __restrict__ semb,
    const float* __restrict__ cw1, const float* __restrict__ cb1,
    const float* __restrict__ cw2, const float* __restrict__ cb2,
    const float* __restrict__ cw3, const float* __restrict__ cb3,
    const float* __restrict__ cw4, const float* __restrict__ cb4,
    float* __restrict__ out)
{
  const int t = threadIdx.x, l = t & 63, w = t >> 6;
  const int b = blockIdx.x * 4 + w;
  __shared__ float cat[4][256];
  __shared__ float hb[4][232];    // h1 128 | h2 64 | h3 32 (+pad)

  // cat staging: one v4f load + store per lane (lanes 0-31: femb, 32-63: semb).
  // cat[w]/hb[w] are wave-private -> no __syncthreads needed anywhere in this kernel;
  // LDS writes by a wave are visible to the same wave after s_waitcnt (compiler-inserted).
  {
    v4f v;
    if (l < 32) v = *(const v4f*)(femb + (size_t)b * 128 + 4 * l);
    else        v = *(const v4f*)(semb + (size_t)b * 128 + 4 * (l - 32));
    *(v4f*)(&cat[w][4 * l]) = v;
  }
  wave_dense<256, 128, true>(cat[w], hb[w], cw1, cb1, l);
  wave_dense<128, 64, true>(hb[w], hb[w] + 128, cw2, cb2, l);
  wave_dense<64, 32, true>(hb[w] + 128, hb[w] + 192, cw3, cb3, l);
  if (l < 4) {
    float acc = cb4[l];
#pragma unroll
    for (int c = 0; c < 32; ++c) acc = fmaf(hb[w][192 + c], cw4[c * 4 + l], acc);
    out[(size_t)b * 4 + l] = (l == 0) ? 21.f / (1.f + expf(-acc)) : 6.f * tanhf(acc);
  }
}

extern "C" void kernel_launch(void* const* d_in, const int* in_sizes, int n_in,
                              void* d_out, int out_size, void* d_ws, size_t ws_size,
                              hipStream_t stream) {
  const float* p[44];
  for (int i = 0; i < 44; ++i) p[i] = (const float*)d_in[i];

  unsigned short* xbar_bf = (unsigned short*)d_ws;                     // 2 MB
  float* femb  = (float*)((char*)d_ws + 2097152);                      // 512 KB
  float* semb  = (float*)((char*)d_ws + 2621440);                      // 512 KB
  unsigned short* wf = (unsigned short*)((char*)d_ws + 3145728);       // 505856 B
  float* mb1p  = (float*)((char*)d_ws + 3651584);                      // 512 B
  float* mb1p7 = (float*)((char*)d_ws + 3652096);                      // 512 B

  prep_weights<<<125, THREADS, 0, stream>>>(
      p[2], p[6], p[10],
      p[14], p[15], p[16], p[17],
      p[18], p[20], p[22], p[24],
      p[26], p[28], p[30], p[32], p[34],
      wf, mb1p, mb1p7);

  pointnet_kernel<<<1024 * S, THREADS, 0, stream>>>(
      p[0],
      wf + WOFF_PNW1, p[4], p[5],
      wf + WOFF_PNW2, p[8], p[9],
      wf + WOFF_PNW3, p[12], p[13],
      xbar_bf);

  tail_mfma_kernel<<<256, THREADS, 0, stream>>>(
      xbar_bf, p[1], wf,
      mb1p, mb1p7, p[19], p[21], p[23], p[25],
      p[27], p[29], p[31], p[33], p[35],
      femb, semb);

  head_kernel<<<256, THREADS, 0, stream>>>(
      femb, semb,
      p[36], p[37], p[38], p[39], p[40], p[41], p[42], p[43],
      (float*)d_out);
}

// Round 13
// 76.010 us; speedup vs baseline: 1.2014x; 1.0583x over previous
//
#include <hip/hip_runtime.h>
#include <hip/hip_bf16.h>
#include <math.h>

#define THREADS 256

constexpr int S   = 8;
constexpr int NPT = 64;
constexpr int SD  = 36;
constexpr float EPS = 1e-5f;

constexpr int NPREP = 119;   // tail-weight pack blocks folded into the pointnet dispatch

typedef float v4f __attribute__((ext_vector_type(4)));
typedef __attribute__((ext_vector_type(8))) short bf8;   // 8 bf16 (4 VGPR)
typedef __attribute__((ext_vector_type(4))) float f4;    // MFMA accumulator

__device__ __forceinline__ float lrelu(float x) { return fmaxf(x, 0.01f * x); }

// float -> bf16 via native HW conversion (RNE)
__device__ __forceinline__ unsigned short f2bf(float x) {
  return __builtin_bit_cast(unsigned short, __float2bfloat16(x));
}

// ==================== fragment packing ====================
// B-fragment: frag f = kt*NT + nt; lane l holds n = nt*16 + (l&15),
// k = kt*32 + (l>>4)*8 + j, j=0..7.
// TS>0: 2-tap conv weight [2][CIN][N], tap stride TS (zero-pad c >= CIN).
// TS==0: flat [K][N]; if CIN>0, zero-pad k >= CIN.
__device__ __forceinline__ void pack_frag(const float* __restrict__ src, unsigned short* __restrict__ dst,
                                          int slot, int NT, int TS, int CIN, int N) {
  const int f = slot >> 6, l = slot & 63;
  const int nt = f % NT, kt = f / NT;
  const int n = nt * 16 + (l & 15), g = (l >> 4);
  unsigned short* d = dst + (size_t)f * 512 + l * 8;
#pragma unroll
  for (int j = 0; j < 8; ++j) {
    int k = kt * 32 + g * 8 + j;
    float v;
    if (TS > 0) { int tap = k / TS, c = k - tap * TS; v = (c < CIN) ? src[(tap * CIN + c) * N + n] : 0.f; }
    else        v = (CIN == 0 || k < CIN) ? src[k * N + n] : 0.f;
    d[j] = f2bf(v);
  }
}

// MW1 fragments with the L4 fold done on the fly:
// W1'[tap][c][n] = sum_d pw4[c][d] * mw1[tap][d][n]   (exact; L4 has no activation)
__device__ __forceinline__ void pack_frag_fold(const float* __restrict__ pw4,
    const float* __restrict__ mw1, unsigned short* __restrict__ dst, int slot) {
  const int f = slot >> 6, l = slot & 63;     // NT = 8
  const int nt = f & 7, kt = f >> 3;
  const int n = nt * 16 + (l & 15), g = l >> 4;
  const int k0 = kt * 32 + g * 8;
  const int tap = k0 >> 7, c0 = k0 & 127;     // 8 consecutive c, single tap
  float acc[8] = {};
  const float* mcol  = mw1 + (size_t)tap * 128 * 128 + n;   // mw1[tap][d][n], d stride 128
  const float* pbase = pw4 + (size_t)c0 * 128;              // pw4[c0+j][d]
  for (int d4 = 0; d4 < 32; ++d4) {
    const int d0 = 4 * d4;
    float m0 = mcol[(size_t)(d0 + 0) * 128];
    float m1 = mcol[(size_t)(d0 + 1) * 128];
    float m2 = mcol[(size_t)(d0 + 2) * 128];
    float m3 = mcol[(size_t)(d0 + 3) * 128];
#pragma unroll
    for (int j = 0; j < 8; ++j) {
      v4f pv = *(const v4f*)(pbase + j * 128 + d0);
      acc[j] = fmaf(pv[0], m0, fmaf(pv[1], m1, fmaf(pv[2], m2, fmaf(pv[3], m3, acc[j]))));
    }
  }
  unsigned short* dd = dst + (size_t)f * 512 + l * 8;
#pragma unroll
  for (int j = 0; j < 8; ++j) dd[j] = f2bf(acc[j]);
}

// fragment-region offsets in u16 units (frag = 512 u16)
#define WOFF_PNW1 0
#define WOFF_PNW2 1024
#define WOFF_PNW3 3072
#define WOFF_MW1  11264
#define WOFF_MW2  44032
#define WOFF_MW3  60416
#define WOFF_MW4  68608
#define WOFF_MDW  76800
#define WOFF_SW1  142336
#define WOFF_SW2  154624
#define WOFF_SW3  171008
#define WOFF_SW4  179200
#define WOFF_SDW  187392
// total 494 frags = 252928 u16 = 505856 B

// ---- tiny prep: pointnet weights only (must precede the pointnet dispatch) ----
__global__ void prep_pn(const float* __restrict__ pw1, const float* __restrict__ pw2,
                        const float* __restrict__ pw3, unsigned short* __restrict__ wf) {
  const int slot = blockIdx.x * 256 + threadIdx.x;
  if      (slot <  128) pack_frag(pw1, wf + WOFF_PNW1, slot,       2, 0,   5,  32);
  else if (slot <  384) pack_frag(pw2, wf + WOFF_PNW2, slot - 128, 4, 0,   0,  64);
  else if (slot < 1408) pack_frag(pw3, wf + WOFF_PNW3, slot - 384, 8, 0,   0, 128);
}

// tail-weight packing, one slot per thread (slot is pre-offset by 1408)
__device__ __forceinline__ void pack_tail_slot(int slot,
    const float* __restrict__ pw4, const float* __restrict__ pb4,
    const float* __restrict__ mw1, const float* __restrict__ mb1,
    const float* __restrict__ mw2, const float* __restrict__ mw3,
    const float* __restrict__ mw4, const float* __restrict__ mdw,
    const float* __restrict__ sw1, const float* __restrict__ sw2, const float* __restrict__ sw3,
    const float* __restrict__ sw4, const float* __restrict__ sdw,
    unsigned short* __restrict__ wf, float* __restrict__ mb1p, float* __restrict__ mb1p7) {
  if      (slot <  5504) pack_frag_fold(pw4, mw1, wf + WOFF_MW1, slot - 1408);
  else if (slot <  7552) pack_frag(mw2,    wf + WOFF_MW2,  slot - 5504,   4, 128, 128,  64);
  else if (slot <  8576) pack_frag(mw3,    wf + WOFF_MW3,  slot - 7552,   4,  64,  64,  64);
  else if (slot <  9600) pack_frag(mw4,    wf + WOFF_MW4,  slot - 8576,   4,  64,  64,  64);
  else if (slot < 17792) pack_frag(mdw,    wf + WOFF_MDW,  slot - 9600,   8,   0,   0, 128);
  else if (slot < 19328) pack_frag(sw1,    wf + WOFF_SW1,  slot - 17792,  8,  48,  36, 128);
  else if (slot < 21376) pack_frag(sw2,    wf + WOFF_SW2,  slot - 19328,  4, 128, 128,  64);
  else if (slot < 22400) pack_frag(sw3,    wf + WOFF_SW3,  slot - 21376,  4,  64,  64,  64);
  else if (slot < 23424) pack_frag(sw4,    wf + WOFF_SW4,  slot - 22400,  4,  64,  64,  64);
  else if (slot < 31616) pack_frag(sdw,    wf + WOFF_SDW,  slot - 23424,  8,   0,   0, 128);
  else if (slot < 31744) {                  // conv1 bias, rows n<7 (both taps see pb4)
    const int n = slot - 31616;
    float a = mb1[n];
    for (int d = 0; d < 128; ++d)
      a = fmaf(pb4[d], mw1[(size_t)d * 128 + n] + mw1[(size_t)(128 + d) * 128 + n], a);
    mb1p[n] = a;
  } else if (slot < 31872) {                // conv1 bias, row n==7 (tap1 input is zero pad)
    const int n = slot - 31744;
    float a = mb1[n];
    for (int d = 0; d < 128; ++d) a = fmaf(pb4[d], mw1[(size_t)d * 128 + n], a);
    mb1p7[n] = a;
  }
}

// ==================== kernel 1: pointnet (+ 119 leading prep blocks) ====================
// Ends at xbar (L4 folded into the tail's conv1); writes 128 bf16 per (b,s).
__global__ __launch_bounds__(THREADS)
void pointnet_kernel(const float* __restrict__ fts,
    const unsigned short* __restrict__ wf,
    const float* __restrict__ pg1, const float* __restrict__ pbe1,
    const float* __restrict__ pg2, const float* __restrict__ pbe2,
    const float* __restrict__ pg3, const float* __restrict__ pbe3,
    // tail-prep inputs (used only by the leading NPREP blocks)
    const float* __restrict__ pw4, const float* __restrict__ pb4,
    const float* __restrict__ mw1, const float* __restrict__ mb1,
    const float* __restrict__ mw2, const float* __restrict__ mw3,
    const float* __restrict__ mw4, const float* __restrict__ mdw,
    const float* __restrict__ sw1, const float* __restrict__ sw2, const float* __restrict__ sw3,
    const float* __restrict__ sw4, const float* __restrict__ sdw,
    unsigned short* __restrict__ wf_out, float* __restrict__ mb1p, float* __restrict__ mb1p7,
    unsigned short* __restrict__ xbar_out)
{
  if (blockIdx.x < NPREP) {   // tail-weight packing, overlapped with pointnet blocks
    pack_tail_slot(blockIdx.x * 256 + threadIdx.x + 1408,
                   pw4, pb4, mw1, mb1, mw2, mw3, mw4, mdw,
                   sw1, sw2, sw3, sw4, sdw, wf_out, mb1p, mb1p7);
    return;
  }
  const int p = blockIdx.x - NPREP;    // b*S + s
  const int t = threadIdx.x;
  const int l = t & 63, w = t >> 6;
  const int g = l >> 4, lc = l & 15;
  const unsigned short* w1f = wf + WOFF_PNW1;
  const unsigned short* w2f = wf + WOFF_PNW2;
  const unsigned short* w3f = wf + WOFF_PNW3;

  __shared__ unsigned short xinb[64 * 40];   // input bf16, K zero-padded to 32 (cols 32..39 unused)
  __shared__ unsigned short x1b[64 * 40];    // L1 normed (ch 0..31)
  __shared__ unsigned short x2b[64 * 72];    // L2 normed (ch 0..63)

  // stage input: thread t owns row t>>2, u32 column slot (t&3)+4k, k=0..3.
  {
    const float* src = fts + (size_t)p * 320;
    unsigned* xz = (unsigned*)xinb;
    const int row = t >> 2, cp = t & 3;
    const float* sr = src + row * 5;
    unsigned v0 = 0u;
    if (cp == 0)      v0 = (unsigned)f2bf(sr[0]) | ((unsigned)f2bf(sr[1]) << 16);
    else if (cp == 1) v0 = (unsigned)f2bf(sr[2]) | ((unsigned)f2bf(sr[3]) << 16);
    else if (cp == 2) v0 = (unsigned)f2bf(sr[4]);
    unsigned* xr = xz + row * 20;
    xr[cp]      = v0;
    xr[cp + 4]  = 0u;
    xr[cp + 8]  = 0u;
    xr[cp + 12] = 0u;
  }
  __syncthreads();

  // ---- L1 MFMA [64x32(k,pad5)]@[32x32]; waves 0,1 own 16 channels each ----
  if (w < 2) {
    f4 c1[4];
#pragma unroll
    for (int mt = 0; mt < 4; ++mt) c1[mt] = f4{0.f, 0.f, 0.f, 0.f};
    bf8 bfrag = *(const bf8*)(w1f + ((size_t)w * 64 + l) * 8);
#pragma unroll
    for (int mt = 0; mt < 4; ++mt) {
      bf8 afrag = *(const bf8*)(xinb + (mt * 16 + lc) * 40 + g * 8);
      c1[mt] = __builtin_amdgcn_mfma_f32_16x16x32_bf16(afrag, bfrag, c1[mt], 0, 0, 0);
    }
    float s = 0.f, q = 0.f;
#pragma unroll
    for (int mt = 0; mt < 4; ++mt)
#pragma unroll
      for (int r = 0; r < 4; ++r) { float v = c1[mt][r]; s += v; q = fmaf(v, v, q); }
    s += __shfl_xor(s, 16, 64); s += __shfl_xor(s, 32, 64);
    q += __shfl_xor(q, 16, 64); q += __shfl_xor(q, 32, 64);
    const int ch = w * 16 + lc;
    float mu  = s * (1.f / NPT);
    float inv = rsqrtf(q * (1.f / NPT) - mu * mu + EPS);
    float a = inv * pg1[ch];
    float bb = fmaf(-mu, a, pbe1[ch]);
#pragma unroll
    for (int mt = 0; mt < 4; ++mt)
#pragma unroll
      for (int r = 0; r < 4; ++r) {
        int row = mt * 16 + g * 4 + r;
        x1b[row * 40 + ch] = f2bf(lrelu(fmaf(c1[mt][r], a, bb)));
      }
  }
  __syncthreads();

  // ---- L2 MFMA [64x32]@[32x64]; wave w owns channels 16w..16w+15 ----
  f4 c2[4];
#pragma unroll
  for (int mt = 0; mt < 4; ++mt) c2[mt] = f4{0.f, 0.f, 0.f, 0.f};
  {
    bf8 bfrag = *(const bf8*)(w2f + ((size_t)w * 64 + l) * 8);
#pragma unroll
    for (int mt = 0; mt < 4; ++mt) {
      bf8 afrag = *(const bf8*)(x1b + (mt * 16 + lc) * 40 + g * 8);
      c2[mt] = __builtin_amdgcn_mfma_f32_16x16x32_bf16(afrag, bfrag, c2[mt], 0, 0, 0);
    }
  }
  {
    float s = 0.f, q = 0.f;
#pragma unroll
    for (int mt = 0; mt < 4; ++mt)
#pragma unroll
      for (int r = 0; r < 4; ++r) { float v = c2[mt][r]; s += v; q = fmaf(v, v, q); }
    s += __shfl_xor(s, 16, 64); s += __shfl_xor(s, 32, 64);
    q += __shfl_xor(q, 16, 64); q += __shfl_xor(q, 32, 64);
    const int ch = w * 16 + lc;
    float mu  = s * (1.f / NPT);
    float inv = rsqrtf(q * (1.f / NPT) - mu * mu + EPS);
    float a = inv * pg2[ch];
    float bb = fmaf(-mu, a, pbe2[ch]);
#pragma unroll
    for (int mt = 0; mt < 4; ++mt)
#pragma unroll
      for (int r = 0; r < 4; ++r) {
        int row = mt * 16 + g * 4 + r;
        x2b[row * 72 + ch] = f2bf(lrelu(fmaf(c2[mt][r], a, bb)));
      }
  }
  __syncthreads();

  // ---- L3 MFMA [64x64]@[64x128]; wave w owns channels 32w..32w+31 ----
  f4 c3[4][2];
#pragma unroll
  for (int mt = 0; mt < 4; ++mt)
#pragma unroll
    for (int n = 0; n < 2; ++n) c3[mt][n] = f4{0.f, 0.f, 0.f, 0.f};
  bf8 bf3[2][2];
#pragma unroll
  for (int ntl = 0; ntl < 2; ++ntl)
#pragma unroll
    for (int kt = 0; kt < 2; ++kt)
      bf3[ntl][kt] = *(const bf8*)(w3f + ((size_t)(kt * 8 + (2 * w + ntl)) * 64 + l) * 8);
#pragma unroll
  for (int mt = 0; mt < 4; ++mt)
#pragma unroll
    for (int kt = 0; kt < 2; ++kt) {
      bf8 afrag = *(const bf8*)(x2b + (mt * 16 + lc) * 72 + kt * 32 + g * 8);
#pragma unroll
      for (int ntl = 0; ntl < 2; ++ntl)
        c3[mt][ntl] = __builtin_amdgcn_mfma_f32_16x16x32_bf16(afrag, bf3[ntl][kt], c3[mt][ntl], 0, 0, 0);
    }

  // ---- inorm3 + lrelu + mean over n, in-register; write xbar bf16 to global ----
#pragma unroll
  for (int ntl = 0; ntl < 2; ++ntl) {
    float s = 0.f, q = 0.f;
#pragma unroll
    for (int mt = 0; mt < 4; ++mt)
#pragma unroll
      for (int r = 0; r < 4; ++r) { float v = c3[mt][ntl][r]; s += v; q = fmaf(v, v, q); }
    s += __shfl_xor(s, 16, 64); s += __shfl_xor(s, 32, 64);
    q += __shfl_xor(q, 16, 64); q += __shfl_xor(q, 32, 64);
    const int ch = w * 32 + ntl * 16 + lc;
    float mu  = s * (1.f / NPT);
    float inv = rsqrtf(q * (1.f / NPT) - mu * mu + EPS);
    float a = inv * pg3[ch];
    float bb = fmaf(-mu, a, pbe3[ch]);
    float m = 0.f;
#pragma unroll
    for (int mt = 0; mt < 4; ++mt)
#pragma unroll
      for (int r = 0; r < 4; ++r) m += lrelu(fmaf(c3[mt][ntl][r], a, bb));
    m += __shfl_xor(m, 16, 64); m += __shfl_xor(m, 32, 64);
    if (g == 0) xbar_out[(size_t)p * 128 + ch] = f2bf(m * (1.f / NPT));
  }
}

// ==================== kernel 2: MFMA tail, G=8 b's per block ====================
// A layout in LDS: [b_loc][9][SP] bf16, row 8 = zeros (2-tap overflow).
// bias7 applies to output rows with n==7 (folded-conv1 edge); pass bias7==bias otherwise.
template<int KT, int NT, int TS, int SPI, int SPO, bool ACT>
__device__ __forceinline__ void mfma_conv(const unsigned short* __restrict__ xin,
    unsigned short* __restrict__ xout, const unsigned short* __restrict__ wfr,
    const float* __restrict__ bias, const float* __restrict__ bias7, int w, int l) {
  const int g = l >> 4, lc = l & 15;
  const int arow = w * 16 + lc, abl = arow >> 3, an = arow & 7;
  f4 acc[NT];
#pragma unroll
  for (int nt = 0; nt < NT; ++nt) acc[nt] = f4{0.f, 0.f, 0.f, 0.f};
#pragma unroll
  for (int kt = 0; kt < KT; ++kt) {
    const int k0 = kt * 32 + g * 8;
    const int tap = k0 / TS, c = k0 - tap * TS;
    bf8 a = *(const bf8*)(xin + (abl * 9 + an + tap) * SPI + c);
#pragma unroll
    for (int nt = 0; nt < NT; ++nt) {
      bf8 b = *(const bf8*)(wfr + ((size_t)(kt * NT + nt) * 64 + l) * 8);
      acc[nt] = __builtin_amdgcn_mfma_f32_16x16x32_bf16(a, b, acc[nt], 0, 0, 0);
    }
  }
  const int orow0 = w * 16 + g * 4;
#pragma unroll
  for (int nt = 0; nt < NT; ++nt) {
    const float bv  = bias[nt * 16 + lc];
    const float bv7 = bias7[nt * 16 + lc];
#pragma unroll
    for (int r = 0; r < 4; ++r) {
      const int rr = orow0 + r, obl = rr >> 3, on = rr & 7;
      float v = acc[nt][r] + (on == 7 ? bv7 : bv);
      if (ACT) v = lrelu(v);
      xout[(obl * 9 + on) * SPO + nt * 16 + lc] = f2bf(v);
    }
  }
}

// dense 512->128 over [8 b][8 n][64 ch] (K-split over 4 waves, partials to LDS)
__device__ __forceinline__ void mfma_dense512(const unsigned short* __restrict__ xin,
    float* __restrict__ P, const unsigned short* __restrict__ wfr, int w, int l) {
  const int g = l >> 4, lc = l & 15;
  const int bl = lc & 7;                 // rows 8-15 duplicate rows 0-7
  f4 acc[8];
#pragma unroll
  for (int nt = 0; nt < 8; ++nt) acc[nt] = f4{0.f, 0.f, 0.f, 0.f};
#pragma unroll
  for (int kt2 = 0; kt2 < 4; ++kt2) {
    const int kt = w * 4 + kt2;
    const int k0 = kt * 32 + g * 8;
    const int n = k0 >> 6, c = k0 & 63;
    bf8 a = *(const bf8*)(xin + (bl * 9 + n) * 72 + c);
#pragma unroll
    for (int nt = 0; nt < 8; ++nt) {
      bf8 b = *(const bf8*)(wfr + ((size_t)(kt * 8 + nt) * 64 + l) * 8);
      acc[nt] = __builtin_amdgcn_mfma_f32_16x16x32_bf16(a, b, acc[nt], 0, 0, 0);
    }
  }
  if (g < 2) {
#pragma unroll
    for (int nt = 0; nt < 8; ++nt)
#pragma unroll
      for (int r = 0; r < 4; ++r) {
        const int rr = g * 4 + r;       // 0..7
        P[(w * 8 + rr) * 128 + nt * 16 + lc] = acc[nt][r];
      }
  }
}

__global__ __launch_bounds__(THREADS)
void tail_mfma_kernel(const unsigned short* __restrict__ xbar, const float* __restrict__ state,
    const unsigned short* __restrict__ wf,
    const float* __restrict__ mb1p, const float* __restrict__ mb1p7,
    const float* __restrict__ mb2, const float* __restrict__ mb3,
    const float* __restrict__ mb4, const float* __restrict__ mdb,
    const float* __restrict__ sb1, const float* __restrict__ sb2, const float* __restrict__ sb3,
    const float* __restrict__ sb4, const float* __restrict__ sdb,
    float* __restrict__ femb, float* __restrict__ semb)
{
  const int t = threadIdx.x, l = t & 63, w = t >> 6;
  const bool merge = blockIdx.x < 128;
  const int bg = merge ? blockIdx.x : blockIdx.x - 128;

  __shared__ unsigned short lds[24768];           // 49.5 KB
  unsigned short* BufX = lds;                     // [8][9][136] xin / L3-out [8][9][72] / partials
  unsigned short* BufY = lds + 9792;              // L1-out [8][9][136] / L4-out [8][9][72]
  unsigned short* BufZ = lds + 19584;             // L2-out [8][9][72]

  // zero: BufX fully; BufY row-8 (stride 136); BufZ row-8 (stride 72)
  { unsigned* z = (unsigned*)BufX; for (int i = t; i < 4896; i += THREADS) z[i] = 0; }
  for (int i = t; i < 8 * 136; i += THREADS) BufY[((i / 136) * 9 + 8) * 136 + (i % 136)] = 0;
  for (int i = t; i < 8 * 72;  i += THREADS) BufZ[((i / 72)  * 9 + 8) * 72  + (i % 72)]  = 0;

  if (merge) {
    for (int i = t; i < 1024; i += THREADS) {     // 8b x 8n x 16 chunks of 8 bf16
      int bl = i >> 7, rem = i & 127, n = rem >> 4, sl = rem & 15;
      bf8 v = *(const bf8*)(xbar + (size_t)((bg * 8 + bl) * 8 + n) * 128 + sl * 8);
      *(bf8*)(BufX + (bl * 9 + n) * 136 + sl * 8) = v;
    }
  } else {
    for (int i = t; i < 2304; i += THREADS) {     // 8b x 8n x 36
      int bl = i / 288, rem = i % 288, n = rem / 36, c = rem % 36;
      BufX[(bl * 9 + n) * 48 + c] = f2bf(state[((size_t)(bg * 8 + bl) * 8 + n) * 36 + c]);
    }
  }
  __syncthreads();

  if (merge) mfma_conv<8, 8, 128, 136, 136, true>(BufX, BufY, wf + WOFF_MW1, mb1p, mb1p7, w, l);
  else       mfma_conv<3, 8,  48,  48, 136, true>(BufX, BufY, wf + WOFF_SW1, sb1, sb1, w, l);
  __syncthreads();
  if (merge) mfma_conv<8, 4, 128, 136, 72, true>(BufY, BufZ, wf + WOFF_MW2, mb2, mb2, w, l);
  else       mfma_conv<8, 4, 128, 136, 72, true>(BufY, BufZ, wf + WOFF_SW2, sb2, sb2, w, l);
  // BufX is dead; set up L3's zero row-8 (stride 72)
  __syncthreads();
  for (int i = t; i < 8 * 72; i += THREADS) BufX[((i / 72) * 9 + 8) * 72 + (i % 72)] = 0;
  __syncthreads();
  if (merge) mfma_conv<4, 4, 64, 72, 72, true>(BufZ, BufX, wf + WOFF_MW3, mb3, mb3, w, l);
  else       mfma_conv<4, 4, 64, 72, 72, true>(BufZ, BufX, wf + WOFF_SW3, sb3, sb3, w, l);
  __syncthreads();
  if (merge) mfma_conv<4, 4, 64, 72, 72, true >(BufX, BufY, wf + WOFF_MW4, mb4, mb4, w, l);
  else       mfma_conv<4, 4, 64, 72, 72, false>(BufX, BufY, wf + WOFF_SW4, sb4, sb4, w, l);
  __syncthreads();

  float* P = (float*)lds;                         // 16 KB partials (BufX region, dead)
  mfma_dense512(BufY, P, wf + (merge ? WOFF_MDW : WOFF_SDW), w, l);
  __syncthreads();

  const float* bias = merge ? mdb : sdb;
  float* outg = (merge ? femb : semb) + (size_t)bg * 1024;
  for (int i = t; i < 1024; i += THREADS) {
    int ch = i & 127, b = i >> 7;
    outg[i] = bias[ch] + P[(0 * 8 + b) * 128 + ch] + P[(1 * 8 + b) * 128 + ch]
                       + P[(2 * 8 + b) * 128 + ch] + P[(3 * 8 + b) * 128 + ch];
  }
}

// ==================== kernel 3: control head, one wave per b (no barriers) ====================
template<int CIN, int COUT, bool ACT>
__device__ __forceinline__ void wave_dense(const float* __restrict__ in, float* __restrict__ out,
                                           const float* __restrict__ W, const float* __restrict__ bias, int l) {
  if constexpr (COUT >= 64) {
    constexpr int NC = COUT / 64;
    const int d0 = l * NC;
    float acc[NC];
#pragma unroll
    for (int k = 0; k < NC; ++k) acc[k] = bias[d0 + k];
#pragma unroll 4
    for (int c4 = 0; c4 < CIN / 4; ++c4) {
      v4f x4 = *(const v4f*)(in + 4 * c4);
#pragma unroll
      for (int j = 0; j < 4; ++j) {
        const float* wr = W + (4 * c4 + j) * COUT + d0;
#pragma unroll
        for (int k = 0; k < NC; ++k) acc[k] = fmaf(x4[j], wr[k], acc[k]);
      }
    }
#pragma unroll
    for (int k = 0; k < NC; ++k) out[d0 + k] = ACT ? lrelu(acc[k]) : acc[k];
  } else {
    if (l < COUT) {
      float acc = bias[l];
#pragma unroll 4
      for (int c4 = 0; c4 < CIN / 4; ++c4) {
        v4f x4 = *(const v4f*)(in + 4 * c4);
#pragma unroll
        for (int j = 0; j < 4; ++j) acc = fmaf(x4[j], W[(4 * c4 + j) * COUT + l], acc);
      }
      out[l] = ACT ? lrelu(acc) : acc;
    }
  }
}

__global__ __launch_bounds__(THREADS)
void head_kernel(const float* __restrict__ femb, const float* __restrict__ semb,
    const float* __restrict__ cw1, const float* __restrict__ cb1,
    const float* __restrict__ cw2, const float* __restrict__ cb2,
    const float* __restrict__ cw3, const float* __restrict__ cb3,
    const float* __restrict__ cw4, const float* __restrict__ cb4,
    float* __restrict__ out)
{
  const int t = threadIdx.x, l = t & 63, w = t >> 6;
  const int b = blockIdx.x * 4 + w;
  __shared__ float cat[4][256];
  __shared__ float hb[4][232];    // h1 128 | h2 64 | h3 32 (+pad)

  // cat staging: one v4f load + store per lane. cat[w]/hb[w] are wave-private ->
  // no __syncthreads needed anywhere in this kernel.
  {
    v4f v;
    if (l < 32) v = *(const v4f*)(femb + (size_t)b * 128 + 4 * l);
    else        v = *(const v4f*)(semb + (size_t)b * 128 + 4 * (l - 32));
    *(v4f*)(&cat[w][4 * l]) = v;
  }
  wave_dense<256, 128, true>(cat[w], hb[w], cw1, cb1, l);
  wave_dense<128, 64, true>(hb[w], hb[w] + 128, cw2, cb2, l);
  wave_dense<64, 32, true>(hb[w] + 128, hb[w] + 192, cw3, cb3, l);
  if (l < 4) {
    float acc = cb4[l];
#pragma unroll
    for (int c = 0; c < 32; ++c) acc = fmaf(hb[w][192 + c], cw4[c * 4 + l], acc);
    out[(size_t)b * 4 + l] = (l == 0) ? 21.f / (1.f + expf(-acc)) : 6.f * tanhf(acc);
  }
}

extern "C" void kernel_launch(void* const* d_in, const int* in_sizes, int n_in,
                              void* d_out, int out_size, void* d_ws, size_t ws_size,
                              hipStream_t stream) {
  const float* p[44];
  for (int i = 0; i < 44; ++i) p[i] = (const float*)d_in[i];

  unsigned short* xbar_bf = (unsigned short*)d_ws;                     // 2 MB
  float* femb  = (float*)((char*)d_ws + 2097152);                      // 512 KB
  float* semb  = (float*)((char*)d_ws + 2621440);                      // 512 KB
  unsigned short* wf = (unsigned short*)((char*)d_ws + 3145728);       // 505856 B
  float* mb1p  = (float*)((char*)d_ws + 3651584);                      // 512 B
  float* mb1p7 = (float*)((char*)d_ws + 3652096);                      // 512 B

  prep_pn<<<6, THREADS, 0, stream>>>(p[2], p[6], p[10], wf);

  pointnet_kernel<<<NPREP + 1024 * S, THREADS, 0, stream>>>(
      p[0], wf,
      p[4], p[5], p[8], p[9], p[12], p[13],
      p[14], p[15], p[16], p[17],
      p[18], p[20], p[22], p[24],
      p[26], p[28], p[30], p[32], p[34],
      wf, mb1p, mb1p7,
      xbar_bf);

  tail_mfma_kernel<<<256, THREADS, 0, stream>>>(
      xbar_bf, p[1], wf,
      mb1p, mb1p7, p[19], p[21], p[23], p[25],
      p[27], p[29], p[31], p[33], p[35],
      femb, semb);

  head_kernel<<<256, THREADS, 0, stream>>>(
      femb, semb,
      p[36], p[37], p[38], p[39], p[40], p[41], p[42], p[43],
      (float*)d_out);
}

// Round 14
// 72.344 us; speedup vs baseline: 1.2622x; 1.0507x over previous
//
#include <hip/hip_runtime.h>
#include <hip/hip_bf16.h>
#include <math.h>

#define THREADS 256

constexpr int S   = 8;
constexpr int NPT = 64;
constexpr int SD  = 36;
constexpr float EPS = 1e-5f;

constexpr int NPREP = 119;   // tail-weight pack blocks folded into the pointnet dispatch

typedef float v4f __attribute__((ext_vector_type(4)));
typedef __attribute__((ext_vector_type(8))) short bf8;   // 8 bf16 (4 VGPR)
typedef __attribute__((ext_vector_type(4))) float f4;    // MFMA accumulator

__device__ __forceinline__ float lrelu(float x) { return fmaxf(x, 0.01f * x); }

// float -> bf16 via native HW conversion (RNE)
__device__ __forceinline__ unsigned short f2bf(float x) {
  return __builtin_bit_cast(unsigned short, __float2bfloat16(x));
}

// ==================== fragment packing ====================
// B-fragment: frag f = kt*NT + nt; lane l holds n = nt*16 + (l&15),
// k = kt*32 + (l>>4)*8 + j, j=0..7.
// TS>0: 2-tap conv weight [2][CIN][N], tap stride TS (zero-pad c >= CIN).
// TS==0: flat [K][N]; if CIN>0, zero-pad k >= CIN.
__device__ __forceinline__ void pack_frag(const float* __restrict__ src, unsigned short* __restrict__ dst,
                                          int slot, int NT, int TS, int CIN, int N) {
  const int f = slot >> 6, l = slot & 63;
  const int nt = f % NT, kt = f / NT;
  const int n = nt * 16 + (l & 15), g = (l >> 4);
  unsigned short* d = dst + (size_t)f * 512 + l * 8;
#pragma unroll
  for (int j = 0; j < 8; ++j) {
    int k = kt * 32 + g * 8 + j;
    float v;
    if (TS > 0) { int tap = k / TS, c = k - tap * TS; v = (c < CIN) ? src[(tap * CIN + c) * N + n] : 0.f; }
    else        v = (CIN == 0 || k < CIN) ? src[k * N + n] : 0.f;
    d[j] = f2bf(v);
  }
}

// MW1 fragments with the L4 fold done on the fly:
// W1'[tap][c][n] = sum_d pw4[c][d] * mw1[tap][d][n]   (exact; L4 has no activation)
// Low-register variant: two passes of 4 output columns, unroll_count(1) on the
// d-loop so the scheduler keeps at most one v4f weight load in flight.
// (R13 lesson: the 8-wide version inflated the WHOLE pointnet kernel to 64 VGPR.)
__device__ __forceinline__ void pack_frag_fold(const float* __restrict__ pw4,
    const float* __restrict__ mw1, unsigned short* __restrict__ dst, int slot) {
  const int f = slot >> 6, l = slot & 63;     // NT = 8
  const int nt = f & 7, kt = f >> 3;
  const int n = nt * 16 + (l & 15), g = l >> 4;
  const int k0 = kt * 32 + g * 8;
  const int tap = k0 >> 7, c0 = k0 & 127;     // 8 consecutive c, single tap
  const float* mcol = mw1 + (size_t)tap * 128 * 128 + n;   // mw1[tap][d][n], d stride 128
  unsigned short* dd = dst + (size_t)f * 512 + l * 8;
#pragma unroll 1
  for (int half = 0; half < 2; ++half) {
    float acc[4] = {};
    const float* pbase = pw4 + (size_t)(c0 + half * 4) * 128;  // pw4[c][d]
#pragma unroll 1
    for (int d4 = 0; d4 < 32; ++d4) {
      const int d0 = 4 * d4;
      float m0 = mcol[(size_t)(d0 + 0) * 128];
      float m1 = mcol[(size_t)(d0 + 1) * 128];
      float m2 = mcol[(size_t)(d0 + 2) * 128];
      float m3 = mcol[(size_t)(d0 + 3) * 128];
#pragma unroll
      for (int j = 0; j < 4; ++j) {
        v4f pv = *(const v4f*)(pbase + j * 128 + d0);
        acc[j] = fmaf(pv[0], m0, fmaf(pv[1], m1, fmaf(pv[2], m2, fmaf(pv[3], m3, acc[j]))));
      }
    }
#pragma unroll
    for (int j = 0; j < 4; ++j) dd[half * 4 + j] = f2bf(acc[j]);
  }
}

// fragment-region offsets in u16 units (frag = 512 u16)
#define WOFF_PNW1 0
#define WOFF_PNW2 1024
#define WOFF_PNW3 3072
#define WOFF_MW1  11264
#define WOFF_MW2  44032
#define WOFF_MW3  60416
#define WOFF_MW4  68608
#define WOFF_MDW  76800
#define WOFF_SW1  142336
#define WOFF_SW2  154624
#define WOFF_SW3  171008
#define WOFF_SW4  179200
#define WOFF_SDW  187392
// total 494 frags = 252928 u16 = 505856 B

// ---- tiny prep: pointnet weights only (must precede the pointnet dispatch) ----
__global__ void prep_pn(const float* __restrict__ pw1, const float* __restrict__ pw2,
                        const float* __restrict__ pw3, unsigned short* __restrict__ wf) {
  const int slot = blockIdx.x * 256 + threadIdx.x;
  if      (slot <  128) pack_frag(pw1, wf + WOFF_PNW1, slot,       2, 0,   5,  32);
  else if (slot <  384) pack_frag(pw2, wf + WOFF_PNW2, slot - 128, 4, 0,   0,  64);
  else if (slot < 1408) pack_frag(pw3, wf + WOFF_PNW3, slot - 384, 8, 0,   0, 128);
}

// tail-weight packing, one slot per thread (slot is pre-offset by 1408)
__device__ __forceinline__ void pack_tail_slot(int slot,
    const float* __restrict__ pw4, const float* __restrict__ pb4,
    const float* __restrict__ mw1, const float* __restrict__ mb1,
    const float* __restrict__ mw2, const float* __restrict__ mw3,
    const float* __restrict__ mw4, const float* __restrict__ mdw,
    const float* __restrict__ sw1, const float* __restrict__ sw2, const float* __restrict__ sw3,
    const float* __restrict__ sw4, const float* __restrict__ sdw,
    unsigned short* __restrict__ wf, float* __restrict__ mb1p, float* __restrict__ mb1p7) {
  if      (slot <  5504) pack_frag_fold(pw4, mw1, wf + WOFF_MW1, slot - 1408);
  else if (slot <  7552) pack_frag(mw2,    wf + WOFF_MW2,  slot - 5504,   4, 128, 128,  64);
  else if (slot <  8576) pack_frag(mw3,    wf + WOFF_MW3,  slot - 7552,   4,  64,  64,  64);
  else if (slot <  9600) pack_frag(mw4,    wf + WOFF_MW4,  slot - 8576,   4,  64,  64,  64);
  else if (slot < 17792) pack_frag(mdw,    wf + WOFF_MDW,  slot - 9600,   8,   0,   0, 128);
  else if (slot < 19328) pack_frag(sw1,    wf + WOFF_SW1,  slot - 17792,  8,  48,  36, 128);
  else if (slot < 21376) pack_frag(sw2,    wf + WOFF_SW2,  slot - 19328,  4, 128, 128,  64);
  else if (slot < 22400) pack_frag(sw3,    wf + WOFF_SW3,  slot - 21376,  4,  64,  64,  64);
  else if (slot < 23424) pack_frag(sw4,    wf + WOFF_SW4,  slot - 22400,  4,  64,  64,  64);
  else if (slot < 31616) pack_frag(sdw,    wf + WOFF_SDW,  slot - 23424,  8,   0,   0, 128);
  else if (slot < 31744) {                  // conv1 bias, rows n<7 (both taps see pb4)
    const int n = slot - 31616;
    float a = mb1[n];
#pragma unroll 1
    for (int d = 0; d < 128; ++d)
      a = fmaf(pb4[d], mw1[(size_t)d * 128 + n] + mw1[(size_t)(128 + d) * 128 + n], a);
    mb1p[n] = a;
  } else if (slot < 31872) {                // conv1 bias, row n==7 (tap1 input is zero pad)
    const int n = slot - 31744;
    float a = mb1[n];
#pragma unroll 1
    for (int d = 0; d < 128; ++d) a = fmaf(pb4[d], mw1[(size_t)d * 128 + n], a);
    mb1p7[n] = a;
  }
}

// ==================== kernel 1: pointnet (+ 119 leading prep blocks) ====================
// Ends at xbar (L4 folded into the tail's conv1); writes 128 bf16 per (b,s).
__global__ __launch_bounds__(THREADS)
void pointnet_kernel(const float* __restrict__ fts,
    const unsigned short* __restrict__ wf,
    const float* __restrict__ pg1, const float* __restrict__ pbe1,
    const float* __restrict__ pg2, const float* __restrict__ pbe2,
    const float* __restrict__ pg3, const float* __restrict__ pbe3,
    // tail-prep inputs (used only by the leading NPREP blocks)
    const float* __restrict__ pw4, const float* __restrict__ pb4,
    const float* __restrict__ mw1, const float* __restrict__ mb1,
    const float* __restrict__ mw2, const float* __restrict__ mw3,
    const float* __restrict__ mw4, const float* __restrict__ mdw,
    const float* __restrict__ sw1, const float* __restrict__ sw2, const float* __restrict__ sw3,
    const float* __restrict__ sw4, const float* __restrict__ sdw,
    unsigned short* __restrict__ wf_out, float* __restrict__ mb1p, float* __restrict__ mb1p7,
    unsigned short* __restrict__ xbar_out)
{
  if (blockIdx.x < NPREP) {   // tail-weight packing, overlapped with pointnet blocks
    pack_tail_slot(blockIdx.x * 256 + threadIdx.x + 1408,
                   pw4, pb4, mw1, mb1, mw2, mw3, mw4, mdw,
                   sw1, sw2, sw3, sw4, sdw, wf_out, mb1p, mb1p7);
    return;
  }
  const int p = blockIdx.x - NPREP;    // b*S + s
  const int t = threadIdx.x;
  const int l = t & 63, w = t >> 6;
  const int g = l >> 4, lc = l & 15;
  const unsigned short* w1f = wf + WOFF_PNW1;
  const unsigned short* w2f = wf + WOFF_PNW2;
  const unsigned short* w3f = wf + WOFF_PNW3;

  __shared__ unsigned short xinb[64 * 40];   // input bf16, K zero-padded to 32 (cols 32..39 unused)
  __shared__ unsigned short x1b[64 * 40];    // L1 normed (ch 0..31)
  __shared__ unsigned short x2b[64 * 72];    // L2 normed (ch 0..63)

  // stage input: thread t owns row t>>2, u32 column slot (t&3)+4k, k=0..3.
  {
    const float* src = fts + (size_t)p * 320;
    unsigned* xz = (unsigned*)xinb;
    const int row = t >> 2, cp = t & 3;
    const float* sr = src + row * 5;
    unsigned v0 = 0u;
    if (cp == 0)      v0 = (unsigned)f2bf(sr[0]) | ((unsigned)f2bf(sr[1]) << 16);
    else if (cp == 1) v0 = (unsigned)f2bf(sr[2]) | ((unsigned)f2bf(sr[3]) << 16);
    else if (cp == 2) v0 = (unsigned)f2bf(sr[4]);
    unsigned* xr = xz + row * 20;
    xr[cp]      = v0;
    xr[cp + 4]  = 0u;
    xr[cp + 8]  = 0u;
    xr[cp + 12] = 0u;
  }
  __syncthreads();

  // ---- L1 MFMA [64x32(k,pad5)]@[32x32]; waves 0,1 own 16 channels each ----
  if (w < 2) {
    f4 c1[4];
#pragma unroll
    for (int mt = 0; mt < 4; ++mt) c1[mt] = f4{0.f, 0.f, 0.f, 0.f};
    bf8 bfrag = *(const bf8*)(w1f + ((size_t)w * 64 + l) * 8);
#pragma unroll
    for (int mt = 0; mt < 4; ++mt) {
      bf8 afrag = *(const bf8*)(xinb + (mt * 16 + lc) * 40 + g * 8);
      c1[mt] = __builtin_amdgcn_mfma_f32_16x16x32_bf16(afrag, bfrag, c1[mt], 0, 0, 0);
    }
    float s = 0.f, q = 0.f;
#pragma unroll
    for (int mt = 0; mt < 4; ++mt)
#pragma unroll
      for (int r = 0; r < 4; ++r) { float v = c1[mt][r]; s += v; q = fmaf(v, v, q); }
    s += __shfl_xor(s, 16, 64); s += __shfl_xor(s, 32, 64);
    q += __shfl_xor(q, 16, 64); q += __shfl_xor(q, 32, 64);
    const int ch = w * 16 + lc;
    float mu  = s * (1.f / NPT);
    float inv = rsqrtf(q * (1.f / NPT) - mu * mu + EPS);
    float a = inv * pg1[ch];
    float bb = fmaf(-mu, a, pbe1[ch]);
#pragma unroll
    for (int mt = 0; mt < 4; ++mt)
#pragma unroll
      for (int r = 0; r < 4; ++r) {
        int row = mt * 16 + g * 4 + r;
        x1b[row * 40 + ch] = f2bf(lrelu(fmaf(c1[mt][r], a, bb)));
      }
  }
  __syncthreads();

  // ---- L2 MFMA [64x32]@[32x64]; wave w owns channels 16w..16w+15 ----
  f4 c2[4];
#pragma unroll
  for (int mt = 0; mt < 4; ++mt) c2[mt] = f4{0.f, 0.f, 0.f, 0.f};
  {
    bf8 bfrag = *(const bf8*)(w2f + ((size_t)w * 64 + l) * 8);
#pragma unroll
    for (int mt = 0; mt < 4; ++mt) {
      bf8 afrag = *(const bf8*)(x1b + (mt * 16 + lc) * 40 + g * 8);
      c2[mt] = __builtin_amdgcn_mfma_f32_16x16x32_bf16(afrag, bfrag, c2[mt], 0, 0, 0);
    }
  }
  {
    float s = 0.f, q = 0.f;
#pragma unroll
    for (int mt = 0; mt < 4; ++mt)
#pragma unroll
      for (int r = 0; r < 4; ++r) { float v = c2[mt][r]; s += v; q = fmaf(v, v, q); }
    s += __shfl_xor(s, 16, 64); s += __shfl_xor(s, 32, 64);
    q += __shfl_xor(q, 16, 64); q += __shfl_xor(q, 32, 64);
    const int ch = w * 16 + lc;
    float mu  = s * (1.f / NPT);
    float inv = rsqrtf(q * (1.f / NPT) - mu * mu + EPS);
    float a = inv * pg2[ch];
    float bb = fmaf(-mu, a, pbe2[ch]);
#pragma unroll
    for (int mt = 0; mt < 4; ++mt)
#pragma unroll
      for (int r = 0; r < 4; ++r) {
        int row = mt * 16 + g * 4 + r;
        x2b[row * 72 + ch] = f2bf(lrelu(fmaf(c2[mt][r], a, bb)));
      }
  }
  __syncthreads();

  // ---- L3 MFMA [64x64]@[64x128]; wave w owns channels 32w..32w+31 ----
  f4 c3[4][2];
#pragma unroll
  for (int mt = 0; mt < 4; ++mt)
#pragma unroll
    for (int n = 0; n < 2; ++n) c3[mt][n] = f4{0.f, 0.f, 0.f, 0.f};
  bf8 bf3[2][2];
#pragma unroll
  for (int ntl = 0; ntl < 2; ++ntl)
#pragma unroll
    for (int kt = 0; kt < 2; ++kt)
      bf3[ntl][kt] = *(const bf8*)(w3f + ((size_t)(kt * 8 + (2 * w + ntl)) * 64 + l) * 8);
#pragma unroll
  for (int mt = 0; mt < 4; ++mt)
#pragma unroll
    for (int kt = 0; kt < 2; ++kt) {
      bf8 afrag = *(const bf8*)(x2b + (mt * 16 + lc) * 72 + kt * 32 + g * 8);
#pragma unroll
      for (int ntl = 0; ntl < 2; ++ntl)
        c3[mt][ntl] = __builtin_amdgcn_mfma_f32_16x16x32_bf16(afrag, bf3[ntl][kt], c3[mt][ntl], 0, 0, 0);
    }

  // ---- inorm3 + lrelu + mean over n, in-register; write xbar bf16 to global ----
#pragma unroll
  for (int ntl = 0; ntl < 2; ++ntl) {
    float s = 0.f, q = 0.f;
#pragma unroll
    for (int mt = 0; mt < 4; ++mt)
#pragma unroll
      for (int r = 0; r < 4; ++r) { float v = c3[mt][ntl][r]; s += v; q = fmaf(v, v, q); }
    s += __shfl_xor(s, 16, 64); s += __shfl_xor(s, 32, 64);
    q += __shfl_xor(q, 16, 64); q += __shfl_xor(q, 32, 64);
    const int ch = w * 32 + ntl * 16 + lc;
    float mu  = s * (1.f / NPT);
    float inv = rsqrtf(q * (1.f / NPT) - mu * mu + EPS);
    float a = inv * pg3[ch];
    float bb = fmaf(-mu, a, pbe3[ch]);
    float m = 0.f;
#pragma unroll
    for (int mt = 0; mt < 4; ++mt)
#pragma unroll
      for (int r = 0; r < 4; ++r) m += lrelu(fmaf(c3[mt][ntl][r], a, bb));
    m += __shfl_xor(m, 16, 64); m += __shfl_xor(m, 32, 64);
    if (g == 0) xbar_out[(size_t)p * 128 + ch] = f2bf(m * (1.f / NPT));
  }
}

// ==================== kernel 2: MFMA tail, G=8 b's per block ====================
// A layout in LDS: [b_loc][9][SP] bf16, row 8 = zeros (2-tap overflow).
// bias7 applies to output rows with n==7 (folded-conv1 edge); pass bias7==bias otherwise.
template<int KT, int NT, int TS, int SPI, int SPO, bool ACT>
__device__ __forceinline__ void mfma_conv(const unsigned short* __restrict__ xin,
    unsigned short* __restrict__ xout, const unsigned short* __restrict__ wfr,
    const float* __restrict__ bias, const float* __restrict__ bias7, int w, int l) {
  const int g = l >> 4, lc = l & 15;
  const int arow = w * 16 + lc, abl = arow >> 3, an = arow & 7;
  f4 acc[NT];
#pragma unroll
  for (int nt = 0; nt < NT; ++nt) acc[nt] = f4{0.f, 0.f, 0.f, 0.f};
#pragma unroll
  for (int kt = 0; kt < KT; ++kt) {
    const int k0 = kt * 32 + g * 8;
    const int tap = k0 / TS, c = k0 - tap * TS;
    bf8 a = *(const bf8*)(xin + (abl * 9 + an + tap) * SPI + c);
#pragma unroll
    for (int nt = 0; nt < NT; ++nt) {
      bf8 b = *(const bf8*)(wfr + ((size_t)(kt * NT + nt) * 64 + l) * 8);
      acc[nt] = __builtin_amdgcn_mfma_f32_16x16x32_bf16(a, b, acc[nt], 0, 0, 0);
    }
  }
  const int orow0 = w * 16 + g * 4;
#pragma unroll
  for (int nt = 0; nt < NT; ++nt) {
    const float bv  = bias[nt * 16 + lc];
    const float bv7 = bias7[nt * 16 + lc];
#pragma unroll
    for (int r = 0; r < 4; ++r) {
      const int rr = orow0 + r, obl = rr >> 3, on = rr & 7;
      float v = acc[nt][r] + (on == 7 ? bv7 : bv);
      if (ACT) v = lrelu(v);
      xout[(obl * 9 + on) * SPO + nt * 16 + lc] = f2bf(v);
    }
  }
}

// dense 512->128 over [8 b][8 n][64 ch] (K-split over 4 waves, partials to LDS)
__device__ __forceinline__ void mfma_dense512(const unsigned short* __restrict__ xin,
    float* __restrict__ P, const unsigned short* __restrict__ wfr, int w, int l) {
  const int g = l >> 4, lc = l & 15;
  const int bl = lc & 7;                 // rows 8-15 duplicate rows 0-7
  f4 acc[8];
#pragma unroll
  for (int nt = 0; nt < 8; ++nt) acc[nt] = f4{0.f, 0.f, 0.f, 0.f};
#pragma unroll
  for (int kt2 = 0; kt2 < 4; ++kt2) {
    const int kt = w * 4 + kt2;
    const int k0 = kt * 32 + g * 8;
    const int n = k0 >> 6, c = k0 & 63;
    bf8 a = *(const bf8*)(xin + (bl * 9 + n) * 72 + c);
#pragma unroll
    for (int nt = 0; nt < 8; ++nt) {
      bf8 b = *(const bf8*)(wfr + ((size_t)(kt * 8 + nt) * 64 + l) * 8);
      acc[nt] = __builtin_amdgcn_mfma_f32_16x16x32_bf16(a, b, acc[nt], 0, 0, 0);
    }
  }
  if (g < 2) {
#pragma unroll
    for (int nt = 0; nt < 8; ++nt)
#pragma unroll
      for (int r = 0; r < 4; ++r) {
        const int rr = g * 4 + r;       // 0..7
        P[(w * 8 + rr) * 128 + nt * 16 + lc] = acc[nt][r];
      }
  }
}

__global__ __launch_bounds__(THREADS)
void tail_mfma_kernel(const unsigned short* __restrict__ xbar, const float* __restrict__ state,
    const unsigned short* __restrict__ wf,
    const float* __restrict__ mb1p, const float* __restrict__ mb1p7,
    const float* __restrict__ mb2, const float* __restrict__ mb3,
    const float* __restrict__ mb4, const float* __restrict__ mdb,
    const float* __restrict__ sb1, const float* __restrict__ sb2, const float* __restrict__ sb3,
    const float* __restrict__ sb4, const float* __restrict__ sdb,
    float* __restrict__ femb, float* __restrict__ semb)
{
  const int t = threadIdx.x, l = t & 63, w = t >> 6;
  const bool merge = blockIdx.x < 128;
  const int bg = merge ? blockIdx.x : blockIdx.x - 128;

  __shared__ unsigned short lds[24768];           // 49.5 KB
  unsigned short* BufX = lds;                     // [8][9][136] xin / L3-out [8][9][72] / partials
  unsigned short* BufY = lds + 9792;              // L1-out [8][9][136] / L4-out [8][9][72]
  unsigned short* BufZ = lds + 19584;             // L2-out [8][9][72]

  // zero: BufX fully; BufY row-8 (stride 136); BufZ row-8 (stride 72)
  { unsigned* z = (unsigned*)BufX; for (int i = t; i < 4896; i += THREADS) z[i] = 0; }
  for (int i = t; i < 8 * 136; i += THREADS) BufY[((i / 136) * 9 + 8) * 136 + (i % 136)] = 0;
  for (int i = t; i < 8 * 72;  i += THREADS) BufZ[((i / 72)  * 9 + 8) * 72  + (i % 72)]  = 0;

  if (merge) {
    for (int i = t; i < 1024; i += THREADS) {     // 8b x 8n x 16 chunks of 8 bf16
      int bl = i >> 7, rem = i & 127, n = rem >> 4, sl = rem & 15;
      bf8 v = *(const bf8*)(xbar + (size_t)((bg * 8 + bl) * 8 + n) * 128 + sl * 8);
      *(bf8*)(BufX + (bl * 9 + n) * 136 + sl * 8) = v;
    }
  } else {
    for (int i = t; i < 2304; i += THREADS) {     // 8b x 8n x 36
      int bl = i / 288, rem = i % 288, n = rem / 36, c = rem % 36;
      BufX[(bl * 9 + n) * 48 + c] = f2bf(state[((size_t)(bg * 8 + bl) * 8 + n) * 36 + c]);
    }
  }
  __syncthreads();

  if (merge) mfma_conv<8, 8, 128, 136, 136, true>(BufX, BufY, wf + WOFF_MW1, mb1p, mb1p7, w, l);
  else       mfma_conv<3, 8,  48,  48, 136, true>(BufX, BufY, wf + WOFF_SW1, sb1, sb1, w, l);
  __syncthreads();
  if (merge) mfma_conv<8, 4, 128, 136, 72, true>(BufY, BufZ, wf + WOFF_MW2, mb2, mb2, w, l);
  else       mfma_conv<8, 4, 128, 136, 72, true>(BufY, BufZ, wf + WOFF_SW2, sb2, sb2, w, l);
  // BufX is dead; set up L3's zero row-8 (stride 72)
  __syncthreads();
  for (int i = t; i < 8 * 72; i += THREADS) BufX[((i / 72) * 9 + 8) * 72 + (i % 72)] = 0;
  __syncthreads();
  if (merge) mfma_conv<4, 4, 64, 72, 72, true>(BufZ, BufX, wf + WOFF_MW3, mb3, mb3, w, l);
  else       mfma_conv<4, 4, 64, 72, 72, true>(BufZ, BufX, wf + WOFF_SW3, sb3, sb3, w, l);
  __syncthreads();
  if (merge) mfma_conv<4, 4, 64, 72, 72, true >(BufX, BufY, wf + WOFF_MW4, mb4, mb4, w, l);
  else       mfma_conv<4, 4, 64, 72, 72, false>(BufX, BufY, wf + WOFF_SW4, sb4, sb4, w, l);
  __syncthreads();

  float* P = (float*)lds;                         // 16 KB partials (BufX region, dead)
  mfma_dense512(BufY, P, wf + (merge ? WOFF_MDW : WOFF_SDW), w, l);
  __syncthreads();

  const float* bias = merge ? mdb : sdb;
  float* outg = (merge ? femb : semb) + (size_t)bg * 1024;
  for (int i = t; i < 1024; i += THREADS) {
    int ch = i & 127, b = i >> 7;
    outg[i] = bias[ch] + P[(0 * 8 + b) * 128 + ch] + P[(1 * 8 + b) * 128 + ch]
                       + P[(2 * 8 + b) * 128 + ch] + P[(3 * 8 + b) * 128 + ch];
  }
}

// ==================== kernel 3: control head, one wave per b (no barriers) ====================
template<int CIN, int COUT, bool ACT>
__device__ __forceinline__ void wave_dense(const float* __restrict__ in, float* __restrict__ out,
                                           const float* __restrict__ W, const float* __restrict__ bias, int l) {
  if constexpr (COUT >= 64) {
    constexpr int NC = COUT / 64;
    const int d0 = l * NC;
    float acc[NC];
#pragma unroll
    for (int k = 0; k < NC; ++k) acc[k] = bias[d0 + k];
#pragma unroll 4
    for (int c4 = 0; c4 < CIN / 4; ++c4) {
      v4f x4 = *(const v4f*)(in + 4 * c4);
#pragma unroll
      for (int j = 0; j < 4; ++j) {
        const float* wr = W + (4 * c4 + j) * COUT + d0;
#pragma unroll
        for (int k = 0; k < NC; ++k) acc[k] = fmaf(x4[j], wr[k], acc[k]);
      }
    }
#pragma unroll
    for (int k = 0; k < NC; ++k) out[d0 + k] = ACT ? lrelu(acc[k]) : acc[k];
  } else {
    if (l < COUT) {
      float acc = bias[l];
#pragma unroll 4
      for (int c4 = 0; c4 < CIN / 4; ++c4) {
        v4f x4 = *(const v4f*)(in + 4 * c4);
#pragma unroll
        for (int j = 0; j < 4; ++j) acc = fmaf(x4[j], W[(4 * c4 + j) * COUT + l], acc);
      }
      out[l] = ACT ? lrelu(acc) : acc;
    }
  }
}

__global__ __launch_bounds__(THREADS)
void head_kernel(const float* __restrict__ femb, const float* __restrict__ semb,
    const float* __restrict__ cw1, const float* __restrict__ cb1,
    const float* __restrict__ cw2, const float* __restrict__ cb2,
    const float* __restrict__ cw3, const float* __restrict__ cb3,
    const float* __restrict__ cw4, const float* __restrict__ cb4,
    float* __restrict__ out)
{
  const int t = threadIdx.x, l = t & 63, w = t >> 6;
  const int b = blockIdx.x * 4 + w;
  __shared__ float cat[4][256];
  __shared__ float hb[4][232];    // h1 128 | h2 64 | h3 32 (+pad)

  // cat staging: one v4f load + store per lane. cat[w]/hb[w] are wave-private ->
  // no __syncthreads needed anywhere in this kernel.
  {
    v4f v;
    if (l < 32) v = *(const v4f*)(femb + (size_t)b * 128 + 4 * l);
    else        v = *(const v4f*)(semb + (size_t)b * 128 + 4 * (l - 32));
    *(v4f*)(&cat[w][4 * l]) = v;
  }
  wave_dense<256, 128, true>(cat[w], hb[w], cw1, cb1, l);
  wave_dense<128, 64, true>(hb[w], hb[w] + 128, cw2, cb2, l);
  wave_dense<64, 32, true>(hb[w] + 128, hb[w] + 192, cw3, cb3, l);
  if (l < 4) {
    float acc = cb4[l];
#pragma unroll
    for (int c = 0; c < 32; ++c) acc = fmaf(hb[w][192 + c], cw4[c * 4 + l], acc);
    out[(size_t)b * 4 + l] = (l == 0) ? 21.f / (1.f + expf(-acc)) : 6.f * tanhf(acc);
  }
}

extern "C" void kernel_launch(void* const* d_in, const int* in_sizes, int n_in,
                              void* d_out, int out_size, void* d_ws, size_t ws_size,
                              hipStream_t stream) {
  const float* p[44];
  for (int i = 0; i < 44; ++i) p[i] = (const float*)d_in[i];

  unsigned short* xbar_bf = (unsigned short*)d_ws;                     // 2 MB
  float* femb  = (float*)((char*)d_ws + 2097152);                      // 512 KB
  float* semb  = (float*)((char*)d_ws + 2621440);                      // 512 KB
  unsigned short* wf = (unsigned short*)((char*)d_ws + 3145728);       // 505856 B
  float* mb1p  = (float*)((char*)d_ws + 3651584);                      // 512 B
  float* mb1p7 = (float*)((char*)d_ws + 3652096);                      // 512 B

  prep_pn<<<6, THREADS, 0, stream>>>(p[2], p[6], p[10], wf);

  pointnet_kernel<<<NPREP + 1024 * S, THREADS, 0, stream>>>(
      p[0], wf,
      p[4], p[5], p[8], p[9], p[12], p[13],
      p[14], p[15], p[16], p[17],
      p[18], p[20], p[22], p[24],
      p[26], p[28], p[30], p[32], p[34],
      wf, mb1p, mb1p7,
      xbar_bf);

  tail_mfma_kernel<<<256, THREADS, 0, stream>>>(
      xbar_bf, p[1], wf,
      mb1p, mb1p7, p[19], p[21], p[23], p[25],
      p[27], p[29], p[31], p[33], p[35],
      femb, semb);

  head_kernel<<<256, THREADS, 0, stream>>>(
      femb, semb,
      p[36], p[37], p[38], p[39], p[40], p[41], p[42], p[43],
      (float*)d_out);
}

// Round 15
// 68.608 us; speedup vs baseline: 1.3310x; 1.0544x over previous
//
#include <hip/hip_runtime.h>
#include <hip/hip_bf16.h>
#include <math.h>

#define THREADS 256

constexpr int S   = 8;
constexpr int NPT = 64;
constexpr int SD  = 36;
constexpr float EPS = 1e-5f;

constexpr int NPREP = 119;   // tail-weight pack blocks folded into the pointnet dispatch

typedef float v4f __attribute__((ext_vector_type(4)));
typedef __attribute__((ext_vector_type(8))) short bf8;   // 8 bf16 (4 VGPR)
typedef __attribute__((ext_vector_type(4))) float f4;    // MFMA accumulator

__device__ __forceinline__ float lrelu(float x) { return fmaxf(x, 0.01f * x); }

// float -> bf16 via native HW conversion (RNE)
__device__ __forceinline__ unsigned short f2bf(float x) {
  return __builtin_bit_cast(unsigned short, __float2bfloat16(x));
}

// ==================== fragment packing ====================
// B-fragment: frag f = kt*NT + nt; lane l holds n = nt*16 + (l&15),
// k = kt*32 + (l>>4)*8 + j, j=0..7.
// TS>0: 2-tap conv weight [2][CIN][N], tap stride TS (zero-pad c >= CIN).
// TS==0: flat [K][N]; if CIN>0, zero-pad k >= CIN.
__device__ __forceinline__ void pack_frag(const float* __restrict__ src, unsigned short* __restrict__ dst,
                                          int slot, int NT, int TS, int CIN, int N) {
  const int f = slot >> 6, l = slot & 63;
  const int nt = f % NT, kt = f / NT;
  const int n = nt * 16 + (l & 15), g = (l >> 4);
  unsigned short* d = dst + (size_t)f * 512 + l * 8;
#pragma unroll
  for (int j = 0; j < 8; ++j) {
    int k = kt * 32 + g * 8 + j;
    float v;
    if (TS > 0) { int tap = k / TS, c = k - tap * TS; v = (c < CIN) ? src[(tap * CIN + c) * N + n] : 0.f; }
    else        v = (CIN == 0 || k < CIN) ? src[k * N + n] : 0.f;
    d[j] = f2bf(v);
  }
}

// MW1 fragments with the L4 fold done on the fly (low-register variant, R14).
__device__ __forceinline__ void pack_frag_fold(const float* __restrict__ pw4,
    const float* __restrict__ mw1, unsigned short* __restrict__ dst, int slot) {
  const int f = slot >> 6, l = slot & 63;     // NT = 8
  const int nt = f & 7, kt = f >> 3;
  const int n = nt * 16 + (l & 15), g = l >> 4;
  const int k0 = kt * 32 + g * 8;
  const int tap = k0 >> 7, c0 = k0 & 127;     // 8 consecutive c, single tap
  const float* mcol = mw1 + (size_t)tap * 128 * 128 + n;   // mw1[tap][d][n], d stride 128
  unsigned short* dd = dst + (size_t)f * 512 + l * 8;
#pragma unroll 1
  for (int half = 0; half < 2; ++half) {
    float acc[4] = {};
    const float* pbase = pw4 + (size_t)(c0 + half * 4) * 128;  // pw4[c][d]
#pragma unroll 1
    for (int d4 = 0; d4 < 32; ++d4) {
      const int d0 = 4 * d4;
      float m0 = mcol[(size_t)(d0 + 0) * 128];
      float m1 = mcol[(size_t)(d0 + 1) * 128];
      float m2 = mcol[(size_t)(d0 + 2) * 128];
      float m3 = mcol[(size_t)(d0 + 3) * 128];
#pragma unroll
      for (int j = 0; j < 4; ++j) {
        v4f pv = *(const v4f*)(pbase + j * 128 + d0);
        acc[j] = fmaf(pv[0], m0, fmaf(pv[1], m1, fmaf(pv[2], m2, fmaf(pv[3], m3, acc[j]))));
      }
    }
#pragma unroll
    for (int j = 0; j < 4; ++j) dd[half * 4 + j] = f2bf(acc[j]);
  }
}

// fragment-region offsets in u16 units (frag = 512 u16)
#define WOFF_PNW1 0
#define WOFF_PNW2 1024
#define WOFF_PNW3 3072
#define WOFF_MW1  11264
#define WOFF_MW2  44032
#define WOFF_MW3  60416
#define WOFF_MW4  68608
#define WOFF_MDW  76800
#define WOFF_SW1  142336
#define WOFF_SW2  154624
#define WOFF_SW3  171008
#define WOFF_SW4  179200
#define WOFF_SDW  187392
// total 494 frags = 252928 u16 = 505856 B

// ---- tiny prep: pointnet weights only (must precede the pointnet dispatch) ----
__global__ void prep_pn(const float* __restrict__ pw1, const float* __restrict__ pw2,
                        const float* __restrict__ pw3, unsigned short* __restrict__ wf) {
  const int slot = blockIdx.x * 256 + threadIdx.x;
  if      (slot <  128) pack_frag(pw1, wf + WOFF_PNW1, slot,       2, 0,   5,  32);
  else if (slot <  384) pack_frag(pw2, wf + WOFF_PNW2, slot - 128, 4, 0,   0,  64);
  else if (slot < 1408) pack_frag(pw3, wf + WOFF_PNW3, slot - 384, 8, 0,   0, 128);
}

// tail-weight packing, one slot per thread (slot is pre-offset by 1408)
__device__ __forceinline__ void pack_tail_slot(int slot,
    const float* __restrict__ pw4, const float* __restrict__ pb4,
    const float* __restrict__ mw1, const float* __restrict__ mb1,
    const float* __restrict__ mw2, const float* __restrict__ mw3,
    const float* __restrict__ mw4, const float* __restrict__ mdw,
    const float* __restrict__ sw1, const float* __restrict__ sw2, const float* __restrict__ sw3,
    const float* __restrict__ sw4, const float* __restrict__ sdw,
    unsigned short* __restrict__ wf, float* __restrict__ mb1p, float* __restrict__ mb1p7) {
  if      (slot <  5504) pack_frag_fold(pw4, mw1, wf + WOFF_MW1, slot - 1408);
  else if (slot <  7552) pack_frag(mw2,    wf + WOFF_MW2,  slot - 5504,   4, 128, 128,  64);
  else if (slot <  8576) pack_frag(mw3,    wf + WOFF_MW3,  slot - 7552,   4,  64,  64,  64);
  else if (slot <  9600) pack_frag(mw4,    wf + WOFF_MW4,  slot - 8576,   4,  64,  64,  64);
  else if (slot < 17792) pack_frag(mdw,    wf + WOFF_MDW,  slot - 9600,   8,   0,   0, 128);
  else if (slot < 19328) pack_frag(sw1,    wf + WOFF_SW1,  slot - 17792,  8,  48,  36, 128);
  else if (slot < 21376) pack_frag(sw2,    wf + WOFF_SW2,  slot - 19328,  4, 128, 128,  64);
  else if (slot < 22400) pack_frag(sw3,    wf + WOFF_SW3,  slot - 21376,  4,  64,  64,  64);
  else if (slot < 23424) pack_frag(sw4,    wf + WOFF_SW4,  slot - 22400,  4,  64,  64,  64);
  else if (slot < 31616) pack_frag(sdw,    wf + WOFF_SDW,  slot - 23424,  8,   0,   0, 128);
  else if (slot < 31744) {                  // conv1 bias, rows n<7 (both taps see pb4)
    const int n = slot - 31616;
    float a = mb1[n];
#pragma unroll 1
    for (int d = 0; d < 128; ++d)
      a = fmaf(pb4[d], mw1[(size_t)d * 128 + n] + mw1[(size_t)(128 + d) * 128 + n], a);
    mb1p[n] = a;
  } else if (slot < 31872) {                // conv1 bias, row n==7 (tap1 input is zero pad)
    const int n = slot - 31744;
    float a = mb1[n];
#pragma unroll 1
    for (int d = 0; d < 128; ++d) a = fmaf(pb4[d], mw1[(size_t)d * 128 + n], a);
    mb1p7[n] = a;
  }
}

// ==================== kernel 1: pointnet (+ 119 leading prep blocks) ====================
// UNCHANGED from R14 (proven ~50 us, VGPR 44).
__global__ __launch_bounds__(THREADS)
void pointnet_kernel(const float* __restrict__ fts,
    const unsigned short* __restrict__ wf,
    const float* __restrict__ pg1, const float* __restrict__ pbe1,
    const float* __restrict__ pg2, const float* __restrict__ pbe2,
    const float* __restrict__ pg3, const float* __restrict__ pbe3,
    const float* __restrict__ pw4, const float* __restrict__ pb4,
    const float* __restrict__ mw1, const float* __restrict__ mb1,
    const float* __restrict__ mw2, const float* __restrict__ mw3,
    const float* __restrict__ mw4, const float* __restrict__ mdw,
    const float* __restrict__ sw1, const float* __restrict__ sw2, const float* __restrict__ sw3,
    const float* __restrict__ sw4, const float* __restrict__ sdw,
    unsigned short* __restrict__ wf_out, float* __restrict__ mb1p, float* __restrict__ mb1p7,
    unsigned short* __restrict__ xbar_out)
{
  if (blockIdx.x < NPREP) {   // tail-weight packing, overlapped with pointnet blocks
    pack_tail_slot(blockIdx.x * 256 + threadIdx.x + 1408,
                   pw4, pb4, mw1, mb1, mw2, mw3, mw4, mdw,
                   sw1, sw2, sw3, sw4, sdw, wf_out, mb1p, mb1p7);
    return;
  }
  const int p = blockIdx.x - NPREP;    // b*S + s
  const int t = threadIdx.x;
  const int l = t & 63, w = t >> 6;
  const int g = l >> 4, lc = l & 15;
  const unsigned short* w1f = wf + WOFF_PNW1;
  const unsigned short* w2f = wf + WOFF_PNW2;
  const unsigned short* w3f = wf + WOFF_PNW3;

  __shared__ unsigned short xinb[64 * 40];
  __shared__ unsigned short x1b[64 * 40];
  __shared__ unsigned short x2b[64 * 72];

  {
    const float* src = fts + (size_t)p * 320;
    unsigned* xz = (unsigned*)xinb;
    const int row = t >> 2, cp = t & 3;
    const float* sr = src + row * 5;
    unsigned v0 = 0u;
    if (cp == 0)      v0 = (unsigned)f2bf(sr[0]) | ((unsigned)f2bf(sr[1]) << 16);
    else if (cp == 1) v0 = (unsigned)f2bf(sr[2]) | ((unsigned)f2bf(sr[3]) << 16);
    else if (cp == 2) v0 = (unsigned)f2bf(sr[4]);
    unsigned* xr = xz + row * 20;
    xr[cp]      = v0;
    xr[cp + 4]  = 0u;
    xr[cp + 8]  = 0u;
    xr[cp + 12] = 0u;
  }
  __syncthreads();

  if (w < 2) {
    f4 c1[4];
#pragma unroll
    for (int mt = 0; mt < 4; ++mt) c1[mt] = f4{0.f, 0.f, 0.f, 0.f};
    bf8 bfrag = *(const bf8*)(w1f + ((size_t)w * 64 + l) * 8);
#pragma unroll
    for (int mt = 0; mt < 4; ++mt) {
      bf8 afrag = *(const bf8*)(xinb + (mt * 16 + lc) * 40 + g * 8);
      c1[mt] = __builtin_amdgcn_mfma_f32_16x16x32_bf16(afrag, bfrag, c1[mt], 0, 0, 0);
    }
    float s = 0.f, q = 0.f;
#pragma unroll
    for (int mt = 0; mt < 4; ++mt)
#pragma unroll
      for (int r = 0; r < 4; ++r) { float v = c1[mt][r]; s += v; q = fmaf(v, v, q); }
    s += __shfl_xor(s, 16, 64); s += __shfl_xor(s, 32, 64);
    q += __shfl_xor(q, 16, 64); q += __shfl_xor(q, 32, 64);
    const int ch = w * 16 + lc;
    float mu  = s * (1.f / NPT);
    float inv = rsqrtf(q * (1.f / NPT) - mu * mu + EPS);
    float a = inv * pg1[ch];
    float bb = fmaf(-mu, a, pbe1[ch]);
#pragma unroll
    for (int mt = 0; mt < 4; ++mt)
#pragma unroll
      for (int r = 0; r < 4; ++r) {
        int row = mt * 16 + g * 4 + r;
        x1b[row * 40 + ch] = f2bf(lrelu(fmaf(c1[mt][r], a, bb)));
      }
  }
  __syncthreads();

  f4 c2[4];
#pragma unroll
  for (int mt = 0; mt < 4; ++mt) c2[mt] = f4{0.f, 0.f, 0.f, 0.f};
  {
    bf8 bfrag = *(const bf8*)(w2f + ((size_t)w * 64 + l) * 8);
#pragma unroll
    for (int mt = 0; mt < 4; ++mt) {
      bf8 afrag = *(const bf8*)(x1b + (mt * 16 + lc) * 40 + g * 8);
      c2[mt] = __builtin_amdgcn_mfma_f32_16x16x32_bf16(afrag, bfrag, c2[mt], 0, 0, 0);
    }
  }
  {
    float s = 0.f, q = 0.f;
#pragma unroll
    for (int mt = 0; mt < 4; ++mt)
#pragma unroll
      for (int r = 0; r < 4; ++r) { float v = c2[mt][r]; s += v; q = fmaf(v, v, q); }
    s += __shfl_xor(s, 16, 64); s += __shfl_xor(s, 32, 64);
    q += __shfl_xor(q, 16, 64); q += __shfl_xor(q, 32, 64);
    const int ch = w * 16 + lc;
    float mu  = s * (1.f / NPT);
    float inv = rsqrtf(q * (1.f / NPT) - mu * mu + EPS);
    float a = inv * pg2[ch];
    float bb = fmaf(-mu, a, pbe2[ch]);
#pragma unroll
    for (int mt = 0; mt < 4; ++mt)
#pragma unroll
      for (int r = 0; r < 4; ++r) {
        int row = mt * 16 + g * 4 + r;
        x2b[row * 72 + ch] = f2bf(lrelu(fmaf(c2[mt][r], a, bb)));
      }
  }
  __syncthreads();

  f4 c3[4][2];
#pragma unroll
  for (int mt = 0; mt < 4; ++mt)
#pragma unroll
    for (int n = 0; n < 2; ++n) c3[mt][n] = f4{0.f, 0.f, 0.f, 0.f};
  bf8 bf3[2][2];
#pragma unroll
  for (int ntl = 0; ntl < 2; ++ntl)
#pragma unroll
    for (int kt = 0; kt < 2; ++kt)
      bf3[ntl][kt] = *(const bf8*)(w3f + ((size_t)(kt * 8 + (2 * w + ntl)) * 64 + l) * 8);
#pragma unroll
  for (int mt = 0; mt < 4; ++mt)
#pragma unroll
    for (int kt = 0; kt < 2; ++kt) {
      bf8 afrag = *(const bf8*)(x2b + (mt * 16 + lc) * 72 + kt * 32 + g * 8);
#pragma unroll
      for (int ntl = 0; ntl < 2; ++ntl)
        c3[mt][ntl] = __builtin_amdgcn_mfma_f32_16x16x32_bf16(afrag, bf3[ntl][kt], c3[mt][ntl], 0, 0, 0);
    }

#pragma unroll
  for (int ntl = 0; ntl < 2; ++ntl) {
    float s = 0.f, q = 0.f;
#pragma unroll
    for (int mt = 0; mt < 4; ++mt)
#pragma unroll
      for (int r = 0; r < 4; ++r) { float v = c3[mt][ntl][r]; s += v; q = fmaf(v, v, q); }
    s += __shfl_xor(s, 16, 64); s += __shfl_xor(s, 32, 64);
    q += __shfl_xor(q, 16, 64); q += __shfl_xor(q, 32, 64);
    const int ch = w * 32 + ntl * 16 + lc;
    float mu  = s * (1.f / NPT);
    float inv = rsqrtf(q * (1.f / NPT) - mu * mu + EPS);
    float a = inv * pg3[ch];
    float bb = fmaf(-mu, a, pbe3[ch]);
    float m = 0.f;
#pragma unroll
    for (int mt = 0; mt < 4; ++mt)
#pragma unroll
      for (int r = 0; r < 4; ++r) m += lrelu(fmaf(c3[mt][ntl][r], a, bb));
    m += __shfl_xor(m, 16, 64); m += __shfl_xor(m, 32, 64);
    if (g == 0) xbar_out[(size_t)p * 128 + ch] = f2bf(m * (1.f / NPT));
  }
}

// ==================== kernel 2: MFMA tail, G=4 b's per block, 512 blocks ====================
// A layout in LDS: [b_loc][9][SP] bf16, row 8 = zeros (2-tap overflow). M = 32 rows.
// Waves: wm = w>>1 owns rows wm*16..wm*16+15; wn = w&1 owns n-tiles [wn*NT/2, (wn+1)*NT/2).
template<int KT, int NT, int TS, int SPI, int SPO, bool ACT>
__device__ __forceinline__ void mfma_conv4(const unsigned short* __restrict__ xin,
    unsigned short* __restrict__ xout, const unsigned short* __restrict__ wfr,
    const float* __restrict__ bias, const float* __restrict__ bias7, int wm, int wn, int l) {
  const int g = l >> 4, lc = l & 15;
  const int arow = wm * 16 + lc, abl = arow >> 3, an = arow & 7;
  constexpr int NTH = NT / 2;
  f4 acc[NTH];
#pragma unroll
  for (int nth = 0; nth < NTH; ++nth) acc[nth] = f4{0.f, 0.f, 0.f, 0.f};
#pragma unroll
  for (int kt = 0; kt < KT; ++kt) {
    const int k0 = kt * 32 + g * 8;
    const int tap = k0 / TS, c = k0 - tap * TS;
    bf8 a = *(const bf8*)(xin + (abl * 9 + an + tap) * SPI + c);
#pragma unroll
    for (int nth = 0; nth < NTH; ++nth) {
      const int nt = wn * NTH + nth;
      bf8 b = *(const bf8*)(wfr + ((size_t)(kt * NT + nt) * 64 + l) * 8);
      acc[nth] = __builtin_amdgcn_mfma_f32_16x16x32_bf16(a, b, acc[nth], 0, 0, 0);
    }
  }
  const int orow0 = wm * 16 + g * 4;
#pragma unroll
  for (int nth = 0; nth < NTH; ++nth) {
    const int nt = wn * NTH + nth;
    const float bv  = bias[nt * 16 + lc];
    const float bv7 = bias7[nt * 16 + lc];
#pragma unroll
    for (int r = 0; r < 4; ++r) {
      const int rr = orow0 + r, obl = rr >> 3, on = rr & 7;
      float v = acc[nth][r] + (on == 7 ? bv7 : bv);
      if (ACT) v = lrelu(v);
      xout[(obl * 9 + on) * SPO + nt * 16 + lc] = f2bf(v);
    }
  }
}

// dense 512->128 over [4 b][8 n][64 ch] (K-split over 4 waves, partials to LDS)
__device__ __forceinline__ void mfma_dense512_g4(const unsigned short* __restrict__ xin,
    float* __restrict__ P, const unsigned short* __restrict__ wfr, int w, int l) {
  const int g = l >> 4, lc = l & 15;
  const int bl = lc & 3;                 // rows 4-15 duplicate rows 0-3
  f4 acc[8];
#pragma unroll
  for (int nt = 0; nt < 8; ++nt) acc[nt] = f4{0.f, 0.f, 0.f, 0.f};
#pragma unroll
  for (int kt2 = 0; kt2 < 4; ++kt2) {
    const int kt = w * 4 + kt2;
    const int k0 = kt * 32 + g * 8;
    const int n = k0 >> 6, c = k0 & 63;
    bf8 a = *(const bf8*)(xin + (bl * 9 + n) * 72 + c);
#pragma unroll
    for (int nt = 0; nt < 8; ++nt) {
      bf8 b = *(const bf8*)(wfr + ((size_t)(kt * 8 + nt) * 64 + l) * 8);
      acc[nt] = __builtin_amdgcn_mfma_f32_16x16x32_bf16(a, b, acc[nt], 0, 0, 0);
    }
  }
  if (g == 0) {                          // rows 0..3 valid (b_loc = row)
#pragma unroll
    for (int nt = 0; nt < 8; ++nt)
#pragma unroll
      for (int r = 0; r < 4; ++r)
        P[(w * 4 + r) * 128 + nt * 16 + lc] = acc[nt][r];
  }
}

__global__ __launch_bounds__(THREADS)
void tail_mfma_kernel(const unsigned short* __restrict__ xbar, const float* __restrict__ state,
    const unsigned short* __restrict__ wf,
    const float* __restrict__ mb1p, const float* __restrict__ mb1p7,
    const float* __restrict__ mb2, const float* __restrict__ mb3,
    const float* __restrict__ mb4, const float* __restrict__ mdb,
    const float* __restrict__ sb1, const float* __restrict__ sb2, const float* __restrict__ sb3,
    const float* __restrict__ sb4, const float* __restrict__ sdb,
    float* __restrict__ femb, float* __restrict__ semb)
{
  const int t = threadIdx.x, l = t & 63, w = t >> 6;
  const int wm = w >> 1, wn = w & 1;
  const bool merge = blockIdx.x < 256;
  const int bg = merge ? blockIdx.x : blockIdx.x - 256;   // group of 4 b's

  __shared__ unsigned short lds[12384];           // 24.75 KB
  unsigned short* BufX = lds;                     // [4][9][136] xin / L3-out [4][9][72] / partials
  unsigned short* BufY = lds + 4896;              // L1-out [4][9][136] / L4-out [4][9][72]
  unsigned short* BufZ = lds + 9792;              // L2-out [4][9][72]

  // zero: BufX fully; BufY row-8 (stride 136); BufZ row-8 (stride 72)
  { unsigned* z = (unsigned*)BufX; for (int i = t; i < 2448; i += THREADS) z[i] = 0; }
  for (int i = t; i < 4 * 136; i += THREADS) BufY[((i / 136) * 9 + 8) * 136 + (i % 136)] = 0;
  if (t < 4 * 72) BufZ[((t / 72) * 9 + 8) * 72 + (t % 72)] = 0;

  if (merge) {
    for (int i = t; i < 512; i += THREADS) {      // 4b x 8n x 16 chunks of 8 bf16
      int bl = i >> 7, rem = i & 127, n = rem >> 4, sl = rem & 15;
      bf8 v = *(const bf8*)(xbar + (size_t)((bg * 4 + bl) * 8 + n) * 128 + sl * 8);
      *(bf8*)(BufX + (bl * 9 + n) * 136 + sl * 8) = v;
    }
  } else {
    for (int i = t; i < 1152; i += THREADS) {     // 4b x 8n x 36
      int bl = i / 288, rem = i % 288, n = rem / 36, c = rem % 36;
      BufX[(bl * 9 + n) * 48 + c] = f2bf(state[((size_t)(bg * 4 + bl) * 8 + n) * 36 + c]);
    }
  }
  __syncthreads();

  if (merge) mfma_conv4<8, 8, 128, 136, 136, true>(BufX, BufY, wf + WOFF_MW1, mb1p, mb1p7, wm, wn, l);
  else       mfma_conv4<3, 8,  48,  48, 136, true>(BufX, BufY, wf + WOFF_SW1, sb1, sb1, wm, wn, l);
  __syncthreads();
  if (merge) mfma_conv4<8, 4, 128, 136, 72, true>(BufY, BufZ, wf + WOFF_MW2, mb2, mb2, wm, wn, l);
  else       mfma_conv4<8, 4, 128, 136, 72, true>(BufY, BufZ, wf + WOFF_SW2, sb2, sb2, wm, wn, l);
  // BufX is dead; set up L3's zero row-8 (stride 72)
  __syncthreads();
  if (t < 4 * 72) BufX[((t / 72) * 9 + 8) * 72 + (t % 72)] = 0;
  __syncthreads();
  if (merge) mfma_conv4<4, 4, 64, 72, 72, true>(BufZ, BufX, wf + WOFF_MW3, mb3, mb3, wm, wn, l);
  else       mfma_conv4<4, 4, 64, 72, 72, true>(BufZ, BufX, wf + WOFF_SW3, sb3, sb3, wm, wn, l);
  __syncthreads();
  if (merge) mfma_conv4<4, 4, 64, 72, 72, true >(BufX, BufY, wf + WOFF_MW4, mb4, mb4, wm, wn, l);
  else       mfma_conv4<4, 4, 64, 72, 72, false>(BufX, BufY, wf + WOFF_SW4, sb4, sb4, wm, wn, l);
  __syncthreads();

  float* P = (float*)lds;                         // 8 KB partials (BufX region, dead)
  mfma_dense512_g4(BufY, P, wf + (merge ? WOFF_MDW : WOFF_SDW), w, l);
  __syncthreads();

  const float* bias = merge ? mdb : sdb;
  float* outg = (merge ? femb : semb) + (size_t)bg * 512;
  for (int i = t; i < 512; i += THREADS) {
    int ch = i & 127, b = i >> 7;
    outg[i] = bias[ch] + P[(0 + b) * 128 + ch] + P[(4 + b) * 128 + ch]
                       + P[(8 + b) * 128 + ch] + P[(12 + b) * 128 + ch];
  }
}

// ==================== kernel 3: control head, one wave per b (no barriers) ====================
template<int CIN, int COUT, bool ACT>
__device__ __forceinline__ void wave_dense(const float* __restrict__ in, float* __restrict__ out,
                                           const float* __restrict__ W, const float* __restrict__ bias, int l) {
  if constexpr (COUT >= 64) {
    constexpr int NC = COUT / 64;
    const int d0 = l * NC;
    float acc[NC];
#pragma unroll
    for (int k = 0; k < NC; ++k) acc[k] = bias[d0 + k];
#pragma unroll 4
    for (int c4 = 0; c4 < CIN / 4; ++c4) {
      v4f x4 = *(const v4f*)(in + 4 * c4);
#pragma unroll
      for (int j = 0; j < 4; ++j) {
        const float* wr = W + (4 * c4 + j) * COUT + d0;
#pragma unroll
        for (int k = 0; k < NC; ++k) acc[k] = fmaf(x4[j], wr[k], acc[k]);
      }
    }
#pragma unroll
    for (int k = 0; k < NC; ++k) out[d0 + k] = ACT ? lrelu(acc[k]) : acc[k];
  } else {
    if (l < COUT) {
      float acc = bias[l];
#pragma unroll 4
      for (int c4 = 0; c4 < CIN / 4; ++c4) {
        v4f x4 = *(const v4f*)(in + 4 * c4);
#pragma unroll
        for (int j = 0; j < 4; ++j) acc = fmaf(x4[j], W[(4 * c4 + j) * COUT + l], acc);
      }
      out[l] = ACT ? lrelu(acc) : acc;
    }
  }
}

__global__ __launch_bounds__(THREADS)
void head_kernel(const float* __restrict__ femb, const float* __restrict__ semb,
    const float* __restrict__ cw1, const float* __restrict__ cb1,
    const float* __restrict__ cw2, const float* __restrict__ cb2,
    const float* __restrict__ cw3, const float* __restrict__ cb3,
    const float* __restrict__ cw4, const float* __restrict__ cb4,
    float* __restrict__ out)
{
  const int t = threadIdx.x, l = t & 63, w = t >> 6;
  const int b = blockIdx.x * 4 + w;
  __shared__ float cat[4][256];
  __shared__ float hb[4][232];    // h1 128 | h2 64 | h3 32 (+pad)

  {
    v4f v;
    if (l < 32) v = *(const v4f*)(femb + (size_t)b * 128 + 4 * l);
    else        v = *(const v4f*)(semb + (size_t)b * 128 + 4 * (l - 32));
    *(v4f*)(&cat[w][4 * l]) = v;
  }
  wave_dense<256, 128, true>(cat[w], hb[w], cw1, cb1, l);
  wave_dense<128, 64, true>(hb[w], hb[w] + 128, cw2, cb2, l);
  wave_dense<64, 32, true>(hb[w] + 128, hb[w] + 192, cw3, cb3, l);
  if (l < 4) {
    float acc = cb4[l];
#pragma unroll
    for (int c = 0; c < 32; ++c) acc = fmaf(hb[w][192 + c], cw4[c * 4 + l], acc);
    out[(size_t)b * 4 + l] = (l == 0) ? 21.f / (1.f + expf(-acc)) : 6.f * tanhf(acc);
  }
}

extern "C" void kernel_launch(void* const* d_in, const int* in_sizes, int n_in,
                              void* d_out, int out_size, void* d_ws, size_t ws_size,
                              hipStream_t stream) {
  const float* p[44];
  for (int i = 0; i < 44; ++i) p[i] = (const float*)d_in[i];

  unsigned short* xbar_bf = (unsigned short*)d_ws;                     // 2 MB
  float* femb  = (float*)((char*)d_ws + 2097152);                      // 512 KB
  float* semb  = (float*)((char*)d_ws + 2621440);                      // 512 KB
  unsigned short* wf = (unsigned short*)((char*)d_ws + 3145728);       // 505856 B
  float* mb1p  = (float*)((char*)d_ws + 3651584);                      // 512 B
  float* mb1p7 = (float*)((char*)d_ws + 3652096);                      // 512 B

  prep_pn<<<6, THREADS, 0, stream>>>(p[2], p[6], p[10], wf);

  pointnet_kernel<<<NPREP + 1024 * S, THREADS, 0, stream>>>(
      p[0], wf,
      p[4], p[5], p[8], p[9], p[12], p[13],
      p[14], p[15], p[16], p[17],
      p[18], p[20], p[22], p[24],
      p[26], p[28], p[30], p[32], p[34],
      wf, mb1p, mb1p7,
      xbar_bf);

  tail_mfma_kernel<<<512, THREADS, 0, stream>>>(
      xbar_bf, p[1], wf,
      mb1p, mb1p7, p[19], p[21], p[23], p[25],
      p[27], p[29], p[31], p[33], p[35],
      femb, semb);

  head_kernel<<<256, THREADS, 0, stream>>>(
      femb, semb,
      p[36], p[37], p[38], p[39], p[40], p[41], p[42], p[43],
      (float*)d_out);
}